// Round 16
// baseline (232.923 us; speedup 1.0000x reference)
//
#include <hip/hip_runtime.h>

#define B_    1024
#define NG_   32
#define F_    16
#define ED_   6
#define EG_   256
#define ET_   262144
#define H1_   5
#define C1_   80
#define HC1_  400
#define C2_   160
#define OBS_  512

#define S1_   408   // LDS bf16 row stride (816B: 16B-aligned, 2-way-max bank alias)
#define SG_   400   // global bf16 row stride
#define CAP_  40960 // packed ego-edge capacity (mean total ~8192)

typedef unsigned short ushort8v __attribute__((ext_vector_type(8)));
typedef _Float16 half2v __attribute__((ext_vector_type(2)));

__device__ __forceinline__ float bf2f(unsigned short u) {
  return __uint_as_float(((unsigned int)u) << 16);
}
__device__ __forceinline__ unsigned short f2bf(float f) {
  unsigned int u = __float_as_uint(f);
  u = u + 0x7FFFu + ((u >> 16) & 1u);   // RNE
  return (unsigned short)(u >> 16);
}
__device__ __forceinline__ unsigned int pack2h(float a, float b) {
  half2v h; h[0] = (_Float16)a; h[1] = (_Float16)b;
  return __builtin_bit_cast(unsigned int, h);
}
__device__ __forceinline__ half2v u2h(unsigned int u) {
  return __builtin_bit_cast(half2v, u);
}
__device__ __forceinline__ float dot8(ushort8v hv, float4 wa, float4 wb, float acc) {
  acc = fmaf(bf2f(hv[0]), wa.x, acc);
  acc = fmaf(bf2f(hv[1]), wa.y, acc);
  acc = fmaf(bf2f(hv[2]), wa.z, acc);
  acc = fmaf(bf2f(hv[3]), wa.w, acc);
  acc = fmaf(bf2f(hv[4]), wb.x, acc);
  acc = fmaf(bf2f(hv[5]), wb.y, acc);
  acc = fmaf(bf2f(hv[6]), wb.z, acc);
  acc = fmaf(bf2f(hv[7]), wb.w, acc);
  return acc;
}

// ---------------------------------------------------------------------------
// K1: node transforms (waves 0-6, into LDS) + bucket build (wave 7) + one
// coalesced LDS->global copy + atomic ego-edge meta packing. Block 0 also
// pre-packs {We triplet (half2 x3), att (f32 bits)} per channel into 16B
// entries for K2/K34 (kernel boundary orders these writes before reads).
// ---------------------------------------------------------------------------
__global__ __launch_bounds__(512, 2)
void k1_transform_bucket(
    const float* __restrict__ x, const int* __restrict__ eidx,
    const float* __restrict__ Wl1, const float* __restrict__ bl1,
    const float* __restrict__ Wr1, const float* __restrict__ br1,
    const float* __restrict__ We1, const float* __restrict__ att1,
    const float* __restrict__ We2, const float* __restrict__ att2,
    unsigned short* __restrict__ xlg, unsigned short* __restrict__ xrg,
    int* __restrict__ eorder_g, int* __restrict__ bstart_g,
    int* __restrict__ packCnt, int* __restrict__ egoOff,
    int* __restrict__ meta_node, int* __restrict__ meta_eid,
    unsigned int* __restrict__ We1h, unsigned int* __restrict__ We2h)
{
  __shared__ __align__(16) unsigned short xlL[NG_ * S1_];
  __shared__ __align__(16) unsigned short xrL[NG_ * S1_];
  __shared__ float xloc[NG_ * F_];
  __shared__ int   edst[EG_];
  __shared__ int   sNE, sStart;
  const int b = blockIdx.x, tid = threadIdx.x;
  const int n0 = b * NG_, eb = b * EG_;

  if (b == 0) {
    for (int i = tid; i < HC1_; i += 512) {
      const float* w = &We1[i * ED_];
      unsigned int* o = &We1h[i * 4];
      o[0] = pack2h(w[0], w[1]); o[1] = pack2h(w[2], w[3]); o[2] = pack2h(w[4], w[5]);
      o[3] = __float_as_uint(att1[i]);
    }
    for (int i = tid; i < C2_; i += 512) {
      const float* w = &We2[i * ED_];
      unsigned int* o = &We2h[i * 4];
      o[0] = pack2h(w[0], w[1]); o[1] = pack2h(w[2], w[3]); o[2] = pack2h(w[4], w[5]);
      o[3] = __float_as_uint(att2[i]);
    }
  }

  if (tid < EG_) edst[tid] = eidx[ET_ + eb + tid] - n0;
  xloc[tid] = x[n0 * F_ + tid];            // NG_*F_ == 512 == blockDim
  __syncthreads();

  if (tid < 448) {
    for (int t = 0; t < 2; ++t) {
      const int ch = tid + t * 448;
      if (ch >= 800) break;
      const bool isL = (ch < 400);
      const int  c   = isL ? ch : ch - 400;
      const float* Wp = (isL ? Wl1 : Wr1) + c * F_;
      const float bias = isL ? bl1[c] : br1[c];
      unsigned short* dst = (isL ? xlL : xrL) + c;
      float w[16];
#pragma unroll
      for (int qk = 0; qk < 4; ++qk) {
        float4 v = *(const float4*)(Wp + qk * 4);
        w[qk*4+0] = v.x; w[qk*4+1] = v.y; w[qk*4+2] = v.z; w[qk*4+3] = v.w;
      }
      for (int n = 0; n < NG_; n += 2) {
        const float* xa = &xloc[n * F_];
        float accA = bias, accB = bias;
#pragma unroll
        for (int qk = 0; qk < 4; ++qk) {
          float4 a  = *(const float4*)(xa + qk * 4);
          float4 bv = *(const float4*)(xa + F_ + qk * 4);
          accA = fmaf(a.x,  w[qk*4+0], accA); accA = fmaf(a.y,  w[qk*4+1], accA);
          accA = fmaf(a.z,  w[qk*4+2], accA); accA = fmaf(a.w,  w[qk*4+3], accA);
          accB = fmaf(bv.x, w[qk*4+0], accB); accB = fmaf(bv.y, w[qk*4+1], accB);
          accB = fmaf(bv.z, w[qk*4+2], accB); accB = fmaf(bv.w, w[qk*4+3], accB);
        }
        dst[n * S1_]       = f2bf(accA);
        dst[(n + 1) * S1_] = f2bf(accB);
      }
    }
  } else {
    const int lane = tid & 63;
    const int d    = lane & 31;
    const int half = lane >> 5;
    int cnt = 0;
    const int4* ed4 = (const int4*)edst;
    for (int i = 0; i < 32; ++i) {
      int4 v = ed4[half * 32 + i];
      cnt += (v.x == d) + (v.y == d) + (v.z == d) + (v.w == d);
    }
    const int cnt_lo = __shfl(cnt, d);
    const int total  = cnt + __shfl_xor(cnt, 32);
    int pre = total;
#pragma unroll
    for (int off = 1; off < 32; off <<= 1) {
      int tt = __shfl(pre, lane - off);
      if (d >= off) pre += tt;
    }
    const int start = pre - total;
    if (lane < 32) {
      bstart_g[b * 33 + d] = start;
      if (d == 31) bstart_g[b * 33 + 32] = pre;
      if (d == 0)  sNE = total;            // ego (local node 0) in-degree
    }
    int p = start + (half ? cnt_lo : 0);
    for (int i = 0; i < 32; ++i) {
      int4 v = ed4[half * 32 + i];
      const int e = half * 128 + i * 4;
      if (v.x == d) eorder_g[eb + p++] = e;
      if (v.y == d) eorder_g[eb + p++] = e + 1;
      if (v.z == d) eorder_g[eb + p++] = e + 2;
      if (v.w == d) eorder_g[eb + p++] = e + 3;
    }
  }
  __syncthreads();

  // coalesced LDS -> global (16B/lane, full cache lines)
  for (int i = tid; i < 3200; i += 512) {
    const bool isR = (i >= 1600);
    const int idx = isR ? i - 1600 : i;
    const int n = idx / 50, c8 = idx - n * 50;
    const ushort8v v = *(const ushort8v*)&(isR ? xrL : xlL)[n * S1_ + c8 * 8];
    *(ushort8v*)&(isR ? xrg : xlg)[(n0 + n) * SG_ + c8 * 8] = v;
  }

  // atomic meta packing (ego bucket = first sNE entries of eorder_g[eb..])
  if (tid == 0) sStart = atomicAdd(packCnt, sNE);
  __syncthreads();
  const int nE = sNE, st = sStart;
  if (tid == 0) egoOff[b] = st;
  if (tid < nE && st + nE <= CAP_) {
    const int e = eorder_g[eb + tid];
    meta_node[st + tid] = eidx[eb + e];     // global src node id
    meta_eid[st + tid]  = eb + e;           // global edge id
  }
}

// ---------------------------------------------------------------------------
// K2: edge scores + segment softmax + aggregation. One block/graph.
// Phase B: one uniform 16B s_load per channel {We triplet, att}.
// ---------------------------------------------------------------------------
__global__ __launch_bounds__(512, 2)
void k2_scores_aggregate(
    const unsigned short* __restrict__ xlg, const unsigned short* __restrict__ xrg,
    const int* __restrict__ eidx, const float* __restrict__ eattr,
    const unsigned int* __restrict__ We1h,
    const float* __restrict__ bc1,
    const int* __restrict__ eorder_g, const int* __restrict__ bstart_g,
    unsigned short* __restrict__ hg)
{
  __shared__ __align__(16) unsigned short xl[NG_ * S1_];
  __shared__ __align__(16) unsigned short xr[NG_ * S1_];
  __shared__ float sc0[EG_ * H1_];
  __shared__ float sc1[EG_ * H1_];
  __shared__ float ea[EG_ * ED_];
  __shared__ int   esrc[EG_], edst[EG_], eorder[EG_];
  __shared__ int   bstart[NG_ + 1];
  __shared__ float deninv[NG_ * H1_];

  const int b = blockIdx.x, tid = threadIdx.x;
  const int n0 = b * NG_, eb = b * EG_;

  for (int i = tid; i < 3200; i += 512) {
    const bool isR = (i >= 1600);
    const int idx = isR ? i - 1600 : i;
    const int n = idx / 50, c8 = idx - n * 50;
    const ushort8v v = *(const ushort8v*)&(isR ? xrg : xlg)[(n0 + n) * SG_ + c8 * 8];
    *(ushort8v*)&(isR ? xr : xl)[n * S1_ + c8 * 8] = v;
  }
  if (tid < EG_) {
    esrc[tid]   = eidx[eb + tid] - n0;
    edst[tid]   = eidx[ET_ + eb + tid] - n0;
    eorder[tid] = eorder_g[eb + tid];
  }
  for (int i = tid; i < EG_ * ED_; i += 512) ea[i] = eattr[eb * ED_ + i];
  if (tid < NG_ + 1) bstart[tid] = bstart_g[b * 33 + tid];
  __syncthreads();

  {
    const int e = tid & 255;
    const int s = __builtin_amdgcn_readfirstlane((int)(tid >> 8) & 1);
    float* const scp = s ? sc1 : sc0;
    const int sl = esrc[e], dl = edst[e];
    const half2v ea01 = { (_Float16)ea[e*ED_+0], (_Float16)ea[e*ED_+1] };
    const half2v ea23 = { (_Float16)ea[e*ED_+2], (_Float16)ea[e*ED_+3] };
    const half2v ea45 = { (_Float16)ea[e*ED_+4], (_Float16)ea[e*ED_+5] };
    const unsigned short* xlrow = &xl[sl * S1_ + s * 40];
    const unsigned short* xrrow = &xr[dl * S1_ + s * 40];
#pragma unroll
    for (int h = 0; h < H1_; ++h) {
      float sh = 0.f;
#pragma unroll
      for (int co = 0; co < 5; ++co) {
        const int coff  = h * C1_ + co * 8;
        const int cbase = coff + s * 40;
        ushort8v av = *(const ushort8v*)(xlrow + coff);
        ushort8v rv = *(const ushort8v*)(xrrow + coff);
#pragma unroll
        for (int u = 0; u < 8; ++u) {
          const uint4 wr4 = *(const uint4*)&We1h[(cbase + u) * 4];  // uniform -> s_load x4
          float ep = __builtin_amdgcn_fdot2(u2h(wr4.z), ea45,
                     __builtin_amdgcn_fdot2(u2h(wr4.y), ea23,
                     __builtin_amdgcn_fdot2(u2h(wr4.x), ea01, 0.f, false), false), false);
          float p = (bf2f(av[u]) + bf2f(rv[u])) + ep;
          p = fmaxf(p, 0.2f * p);
          sh = fmaf(p, __uint_as_float(wr4.w), sh);
        }
      }
      scp[e * H1_ + h] = sh;
    }
  }
  __syncthreads();

  if (tid < NG_ * H1_) {
    const int d = tid & 31, h = tid >> 5;
    const int s0 = bstart[d], s1 = bstart[d + 1];
    float m = -INFINITY;
    for (int k = s0; k < s1; ++k) {
      const int e5i = eorder[k] * H1_ + h;
      m = fmaxf(m, sc0[e5i] + sc1[e5i]);
    }
    float den = 0.f;
    for (int k = s0; k < s1; ++k) {
      const int e5i = eorder[k] * H1_ + h;
      float t = expf(sc0[e5i] + sc1[e5i] - m);
      den += t;
      sc0[e5i] = t;
    }
    deninv[tid] = 1.f / (den + 1e-16f);
  }
  __syncthreads();

  for (int idx = tid; idx < NG_ * 50; idx += 512) {
    const int d  = idx / 50;
    const int co = idx - d * 50;
    const int c  = co * 8;
    const int h  = co / 10;
    const int s0 = bstart[d], s1 = bstart[d + 1];
    float acc[8] = {0.f,0.f,0.f,0.f,0.f,0.f,0.f,0.f};
    for (int k = s0; k < s1; ++k) {
      const int e = eorder[k];
      const float al = sc0[e * H1_ + h];
      ushort8v xv = *(const ushort8v*)(&xl[esrc[e] * S1_ + c]);
#pragma unroll
      for (int u = 0; u < 8; ++u) acc[u] = fmaf(al, bf2f(xv[u]), acc[u]);
    }
    const float inv = deninv[h * 32 + d];
    ushort8v hv;
#pragma unroll
    for (int u = 0; u < 8; ++u)
      hv[u] = f2bf(fmaxf(fmaf(acc[u], inv, bc1[c + u]), 0.f));
    *(ushort8v*)&hg[(n0 + d) * SG_ + c] = hv;
  }
}

// ---------------------------------------------------------------------------
// K3a: packed GEMM. Blocks 0..15: xr2v = ego rows @ Wr2^T (+br2). Blocks
// 16..: grid-stride over packed ego-edge rows, msg = rows @ Wl2^T (+bl2).
// ---------------------------------------------------------------------------
__global__ __launch_bounds__(512, 2)
void k3a_gemm(const unsigned short* __restrict__ hg,
              const int* __restrict__ meta_node, const int* __restrict__ packCnt,
              const float* __restrict__ Wl2, const float* __restrict__ bl2,
              const float* __restrict__ Wr2, const float* __restrict__ br2,
              float* __restrict__ msgP, float* __restrict__ xr2v_g)
{
  __shared__ __align__(16) unsigned short rows[64 * S1_];
  __shared__ int rnode[64];
  __shared__ int sTot;
  const int tid = threadIdx.x;
  const bool isX = (blockIdx.x < 16);
  if (tid == 0) sTot = *packCnt;
  __syncthreads();
  const int total = min(sTot, CAP_);

  const float* W    = isX ? Wr2 : Wl2;
  const float* bias = isX ? br2 : bl2;
  float* outB       = isX ? xr2v_g : msgP;

  const int es = tid & 15;      // edge slot (rows es, es+16, es+32, es+48)
  const int cg = tid >> 4;      // cc group -> cc = cg*5 + {0..4}
  const float* wp[5];
#pragma unroll
  for (int i = 0; i < 5; ++i) wp[i] = &W[(size_t)(cg * 5 + i) * HC1_];

  int c = isX ? (int)blockIdx.x : (int)blockIdx.x - 16;
  const int cstep = (int)gridDim.x - 16;

  for (;;) {
    const int r0 = c * 64;
    int nr;
    if (isX) nr = 64;
    else { if (r0 >= total) break; nr = min(64, total - r0); }

    __syncthreads();
    if (tid < 64) rnode[tid] = (tid < nr) ? (isX ? (r0 + tid) * NG_ : meta_node[r0 + tid]) : 0;
    __syncthreads();
    for (int i = tid; i < 64 * 50; i += 512) {
      const int r = i / 50, o8 = i - r * 50;
      if (r < nr)
        *(ushort8v*)&rows[r * S1_ + o8 * 8] =
            *(const ushort8v*)&hg[(size_t)rnode[r] * SG_ + o8 * 8];
    }
    __syncthreads();

    float acc[4][5] = {};
#pragma unroll 2
    for (int ko = 0; ko < 50; ++ko) {
      const int k = ko * 8;
      ushort8v rv[4];
#pragma unroll
      for (int t = 0; t < 4; ++t)
        rv[t] = *(const ushort8v*)&rows[(es + 16 * t) * S1_ + k];
#pragma unroll
      for (int i = 0; i < 5; ++i) {
        const float4 wa = *(const float4*)(wp[i] + k);
        const float4 wb = *(const float4*)(wp[i] + k + 4);
#pragma unroll
        for (int t = 0; t < 4; ++t)
          acc[t][i] = dot8(rv[t], wa, wb, acc[t][i]);
      }
    }

#pragma unroll
    for (int t = 0; t < 4; ++t) {
      const int r = es + 16 * t;
      if (r < nr) {
        float* op = outB + (size_t)(r0 + r) * C2_ + cg * 5;
#pragma unroll
        for (int i = 0; i < 5; ++i) op[i] = acc[t][i] + bias[cg * 5 + i];
      }
    }
    if (isX) break;
    c += cstep;
  }
}

// ---------------------------------------------------------------------------
// K34: fused per-graph layer-2 finisher + dense head + MLP. 256 blocks x 512.
// Score loop uses fdot2 on pre-packed We2h; att2 rides in the 4th dword.
// ---------------------------------------------------------------------------
__global__ __launch_bounds__(512, 2)
void k34_finish_mlp(
    const float* __restrict__ eattr,
    const unsigned int* __restrict__ We2h,
    const float* __restrict__ bc2,
    const int* __restrict__ egoOff, const int* __restrict__ bstart_g,
    const int* __restrict__ meta_eid,
    const float* __restrict__ msgP, const float* __restrict__ xr2v_g,
    const float* __restrict__ Wd1, const float* __restrict__ bd1,
    const float* __restrict__ Wd2, const float* __restrict__ bd2,
    const float* __restrict__ Wf1, const float* __restrict__ bf1,
    const float* __restrict__ Wf2, const float* __restrict__ bf2,
    const float* __restrict__ Wm,  const float* __restrict__ bm,
    const float* __restrict__ Ws,  const float* __restrict__ bs,
    float* __restrict__ out)
{
  __shared__ float hE[4 * C2_];
  __shared__ float t1[4 * NG_];
  __shared__ float dbuf[4 * OBS_];
  __shared__ float f1b[4 * 256];
  __shared__ float f2b[4 * 256];
  __shared__ float xr2s[4 * C2_];
  __shared__ float scq[4 * EG_], wq4[4 * EG_];
  __shared__ float sInv[4];

  const int g0  = blockIdx.x * 4;
  const int tid = threadIdx.x;
  const int tg  = tid >> 7;          // graph group 0..3
  const int lt  = tid & 127;
  const int g   = g0 + tg;
  const int off = egoOff[g];
  const int nE  = bstart_g[g * 33 + 1];

  if (lt < 40)
    *(float4*)&xr2s[tg * C2_ + lt * 4] = *(const float4*)&xr2v_g[(size_t)g * C2_ + lt * 4];
  __syncthreads();

  // ---- scores: 8 lanes/edge, 16 edges per pass per graph ----
  {
    const int s = lt >> 3, q8 = lt & 7;
    for (int base = 0; base < nE; base += 16) {
      const int j = base + s;
      float sv = 0.f;
      if (j < nE) {
        const int eid = meta_eid[off + j];
        const float* ap = &eattr[(size_t)eid * ED_];
        const half2v ea01 = { (_Float16)ap[0], (_Float16)ap[1] };
        const half2v ea23 = { (_Float16)ap[2], (_Float16)ap[3] };
        const half2v ea45 = { (_Float16)ap[4], (_Float16)ap[5] };
        const float* mrow = &msgP[(size_t)(off + j) * C2_];
        const float* xrv  = &xr2s[tg * C2_];
        for (int i = 0; i < 20; ++i) {
          const int c2 = q8 * 20 + i;
          const uint4 wv4 = *(const uint4*)&We2h[c2 * 4];
          float ep = __builtin_amdgcn_fdot2(u2h(wv4.z), ea45,
                     __builtin_amdgcn_fdot2(u2h(wv4.y), ea23,
                     __builtin_amdgcn_fdot2(u2h(wv4.x), ea01, 0.f, false), false), false);
          float pp = mrow[c2] + xrv[c2] + ep;
          pp = fmaxf(pp, 0.2f * pp);
          sv = fmaf(pp, __uint_as_float(wv4.w), sv);
        }
      }
      sv += __shfl_xor(sv, 1); sv += __shfl_xor(sv, 2); sv += __shfl_xor(sv, 4);
      if (q8 == 0 && j < nE) scq[tg * EG_ + j] = sv;
    }
  }
  __syncthreads();

  // ---- softmax: first wave of each 128-thread group ----
  if (lt < 64) {
    float m = -INFINITY;
    for (int j = lt; j < nE; j += 64) m = fmaxf(m, scq[tg * EG_ + j]);
#pragma unroll
    for (int d = 1; d < 64; d <<= 1) m = fmaxf(m, __shfl_xor(m, d));
    float den = 0.f;
    for (int j = lt; j < nE; j += 64) {
      const float w = expf(scq[tg * EG_ + j] - m);
      wq4[tg * EG_ + j] = w;
      den += w;
    }
#pragma unroll
    for (int d = 1; d < 64; d <<= 1) den += __shfl_xor(den, d);
    if (lt == 0) sInv[tg] = 1.f / (den + 1e-16f);
  }
  __syncthreads();

  // ---- accumulate + finalize straight into hE ----
  for (int c = lt; c < C2_; c += 128) {
    float o = 0.f;
    for (int j = 0; j < nE; ++j)
      o = fmaf(wq4[tg * EG_ + j], msgP[(size_t)(off + j) * C2_ + c], o);
    hE[tg * C2_ + c] = fmaxf(fmaf(o, sInv[tg], bc2[c]), 0.f);
  }
  __syncthreads();

  // ---- MLP body ----
  if (tid < 4 * NG_) {
    const int gg = tid >> 5, o = tid & 31;
    float acc = bd1[o];
    const float* w  = &Wd1[o * C2_];
    const float* hp = &hE[gg * C2_];
    for (int k = 0; k < C2_; k += 4) {
      float4 hv = *(const float4*)(hp + k);
      float4 wv = *(const float4*)(w + k);
      acc = fmaf(hv.x, wv.x, acc); acc = fmaf(hv.y, wv.y, acc);
      acc = fmaf(hv.z, wv.z, acc); acc = fmaf(hv.w, wv.w, acc);
    }
    t1[tid] = acc;
  }
  __syncthreads();

  for (int idx = tid; idx < 4 * OBS_; idx += 512) {
    const int gg = idx >> 9, o = idx & 511;
    float acc = bd2[o];
    const float* w  = &Wd2[o * NG_];
    const float* tp = &t1[gg * NG_];
#pragma unroll
    for (int k = 0; k < NG_; k += 4) {
      float4 tv = *(const float4*)(tp + k);
      float4 wv = *(const float4*)(w + k);
      acc = fmaf(tv.x, wv.x, acc); acc = fmaf(tv.y, wv.y, acc);
      acc = fmaf(tv.z, wv.z, acc); acc = fmaf(tv.w, wv.w, acc);
    }
    dbuf[idx] = tanhf(acc);
  }
  __syncthreads();

  {
    const int o = tid & 255, gg = tid >> 8;
    const float* w  = &Wf1[o * OBS_];
    const float* dA = &dbuf[(gg * 2 + 0) * OBS_];
    const float* dB = &dbuf[(gg * 2 + 1) * OBS_];
    float a0 = bf1[o], a1 = a0;
#pragma unroll 2
    for (int k = 0; k < OBS_; k += 4) {
      float4 wv = *(const float4*)(w + k);
      float4 xA = *(const float4*)(dA + k);
      float4 xB = *(const float4*)(dB + k);
      a0 = fmaf(xA.x, wv.x, a0); a0 = fmaf(xA.y, wv.y, a0);
      a0 = fmaf(xA.z, wv.z, a0); a0 = fmaf(xA.w, wv.w, a0);
      a1 = fmaf(xB.x, wv.x, a1); a1 = fmaf(xB.y, wv.y, a1);
      a1 = fmaf(xB.z, wv.z, a1); a1 = fmaf(xB.w, wv.w, a1);
    }
    f1b[(gg * 2 + 0) * 256 + o] = fmaxf(a0, 0.f);
    f1b[(gg * 2 + 1) * 256 + o] = fmaxf(a1, 0.f);
  }
  __syncthreads();

  {
    const int o = tid & 255, gg = tid >> 8;
    const float* w  = &Wf2[o * 256];
    const float* dA = &f1b[(gg * 2 + 0) * 256];
    const float* dB = &f1b[(gg * 2 + 1) * 256];
    float a0 = bf2[o], a1 = a0;
#pragma unroll 2
    for (int k = 0; k < 256; k += 4) {
      float4 wv = *(const float4*)(w + k);
      float4 xA = *(const float4*)(dA + k);
      float4 xB = *(const float4*)(dB + k);
      a0 = fmaf(xA.x, wv.x, a0); a0 = fmaf(xA.y, wv.y, a0);
      a0 = fmaf(xA.z, wv.z, a0); a0 = fmaf(xA.w, wv.w, a0);
      a1 = fmaf(xB.x, wv.x, a1); a1 = fmaf(xB.y, wv.y, a1);
      a1 = fmaf(xB.z, wv.z, a1); a1 = fmaf(xB.w, wv.w, a1);
    }
    f2b[(gg * 2 + 0) * 256 + o] = fmaxf(a0, 0.f);
    f2b[(gg * 2 + 1) * 256 + o] = fmaxf(a1, 0.f);
  }
  __syncthreads();

  if (tid < 16) {
    const int gg = tid >> 2;
    const int a  = (tid >> 1) & 1;
    const int hm = tid & 1;
    const float* fp = &f2b[gg * 256];
    const float* w  = hm ? &Ws[a * 256] : &Wm[a * 256];
    float acc = hm ? bs[a] : bm[a];
    for (int k = 0; k < 256; ++k) acc = fmaf(fp[k], w[k], acc);
    if (hm == 0) out[(g0 + gg) * 2 + a] = acc;
    else         out[2048 + (g0 + gg) * 2 + a] = -5.0f + 3.5f * (tanhf(acc) + 1.0f);
  }
}

extern "C" void kernel_launch(void* const* d_in, const int* in_sizes, int n_in,
                              void* d_out, int out_size, void* d_ws, size_t ws_size,
                              hipStream_t stream) {
  const float* x     = (const float*)d_in[0];
  const int*   eidx  = (const int*)d_in[1];
  const float* eattr = (const float*)d_in[2];
  const float* Wl1 = (const float*)d_in[3];  const float* bl1 = (const float*)d_in[4];
  const float* Wr1 = (const float*)d_in[5];  const float* br1 = (const float*)d_in[6];
  const float* We1 = (const float*)d_in[7];  const float* att1= (const float*)d_in[8];
  const float* bc1 = (const float*)d_in[9];
  const float* Wl2 = (const float*)d_in[10]; const float* bl2 = (const float*)d_in[11];
  const float* Wr2 = (const float*)d_in[12]; const float* br2 = (const float*)d_in[13];
  const float* We2 = (const float*)d_in[14]; const float* att2= (const float*)d_in[15];
  const float* bc2 = (const float*)d_in[16];
  const float* Wd1 = (const float*)d_in[17]; const float* bd1 = (const float*)d_in[18];
  const float* Wd2 = (const float*)d_in[19]; const float* bd2 = (const float*)d_in[20];
  const float* Wf1 = (const float*)d_in[21]; const float* bf1 = (const float*)d_in[22];
  const float* Wf2 = (const float*)d_in[23]; const float* bf2 = (const float*)d_in[24];
  const float* Wm  = (const float*)d_in[25]; const float* bm  = (const float*)d_in[26];
  const float* Ws  = (const float*)d_in[27]; const float* bs  = (const float*)d_in[28];

  // workspace layout (~82 MB)
  unsigned short* xlg = (unsigned short*)d_ws;          // [32768][400] bf16 = 26.2 MB
  unsigned short* hg  = xlg + (size_t)32768 * SG_;      // xr, then h     = 26.2 MB
  float* msgP   = (float*)(hg + (size_t)32768 * SG_);   // CAP_ x 160 f32 = 26.2 MB
  int* eorder_g = (int*)(msgP + (size_t)CAP_ * C2_);    // 1.05 MB
  int* bstart_g = eorder_g + ET_;                       // 132 KB
  float* egoHu  = (float*)(bstart_g + B_ * 33);         // 640 KB (unused, layout keep)
  int* egoOff   = (int*)(egoHu + B_ * C2_);             // 4.1 KB
  int* meta_node= egoOff + (B_ + 1);                    // 160 KB
  int* meta_eid = meta_node + CAP_;                     // 160 KB
  float* xr2v_g = (float*)(meta_eid + CAP_);            // 640 KB
  int* packCnt  = (int*)(xr2v_g + B_ * C2_);            // 4 B
  unsigned int* We1h = (unsigned int*)(packCnt + 4);    // 6.4 KB
  unsigned int* We2h = We1h + HC1_ * 4;                 // 2.6 KB

  hipMemsetAsync(packCnt, 0, sizeof(int), stream);

  k1_transform_bucket<<<B_, 512, 0, stream>>>(
      x, eidx, Wl1, bl1, Wr1, br1, We1, att1, We2, att2,
      xlg, hg, eorder_g, bstart_g,
      packCnt, egoOff, meta_node, meta_eid, We1h, We2h);

  k2_scores_aggregate<<<B_, 512, 0, stream>>>(
      xlg, hg, eidx, eattr, We1h, bc1, eorder_g, bstart_g, hg);

  k3a_gemm<<<272, 512, 0, stream>>>(
      hg, meta_node, packCnt, Wl2, bl2, Wr2, br2, msgP, xr2v_g);

  k34_finish_mlp<<<B_ / 4, 512, 0, stream>>>(
      eattr, We2h, bc2, egoOff, bstart_g, meta_eid, msgP, xr2v_g,
      Wd1, bd1, Wd2, bd2, Wf1, bf1, Wf2, bf2, Wm, bm, Ws, bs,
      (float*)d_out);
}

// Round 17
// 220.794 us; speedup vs baseline: 1.0549x; 1.0549x over previous
//
#include <hip/hip_runtime.h>

#define B_    1024
#define NG_   32
#define F_    16
#define ED_   6
#define EG_   256
#define ET_   262144
#define H1_   5
#define C1_   80
#define HC1_  400
#define C2_   160
#define OBS_  512

#define S1_   408   // LDS f16 row stride (816B: 16B-aligned, 2-way-max bank alias)
#define SG_   400   // global f16/bf16 row stride
#define CAP_  40960 // packed ego-edge capacity (mean total ~8192)

typedef unsigned short ushort8v __attribute__((ext_vector_type(8)));
typedef _Float16 half2v __attribute__((ext_vector_type(2)));

__device__ __forceinline__ float bf2f(unsigned short u) {
  return __uint_as_float(((unsigned int)u) << 16);
}
__device__ __forceinline__ unsigned short f2bf(float f) {
  unsigned int u = __float_as_uint(f);
  u = u + 0x7FFFu + ((u >> 16) & 1u);   // RNE
  return (unsigned short)(u >> 16);
}
__device__ __forceinline__ unsigned short f2h(float f) {
  return __builtin_bit_cast(unsigned short, (_Float16)f);
}
__device__ __forceinline__ float h2f(unsigned short u) {
  return (float)__builtin_bit_cast(_Float16, u);
}
__device__ __forceinline__ unsigned int pack2h(float a, float b) {
  half2v h; h[0] = (_Float16)a; h[1] = (_Float16)b;
  return __builtin_bit_cast(unsigned int, h);
}
__device__ __forceinline__ half2v u2h(unsigned int u) {
  return __builtin_bit_cast(half2v, u);
}
__device__ __forceinline__ float dot8(ushort8v hv, float4 wa, float4 wb, float acc) {
  acc = fmaf(bf2f(hv[0]), wa.x, acc);
  acc = fmaf(bf2f(hv[1]), wa.y, acc);
  acc = fmaf(bf2f(hv[2]), wa.z, acc);
  acc = fmaf(bf2f(hv[3]), wa.w, acc);
  acc = fmaf(bf2f(hv[4]), wb.x, acc);
  acc = fmaf(bf2f(hv[5]), wb.y, acc);
  acc = fmaf(bf2f(hv[6]), wb.z, acc);
  acc = fmaf(bf2f(hv[7]), wb.w, acc);
  return acc;
}

// ---------------------------------------------------------------------------
// K1: node transforms (waves 0-6, into LDS, f16) + bucket build (wave 7) +
// coalesced LDS->global copy + atomic ego-edge meta packing. Block 0 packs
// We1 pair-layout (8 dwords/channel-pair: 6x interleaved half2 + att half2 +
// pad) and We2h (16B/channel with att in .w).
// ---------------------------------------------------------------------------
__global__ __launch_bounds__(512, 2)
void k1_transform_bucket(
    const float* __restrict__ x, const int* __restrict__ eidx,
    const float* __restrict__ Wl1, const float* __restrict__ bl1,
    const float* __restrict__ Wr1, const float* __restrict__ br1,
    const float* __restrict__ We1, const float* __restrict__ att1,
    const float* __restrict__ We2, const float* __restrict__ att2,
    unsigned short* __restrict__ xlg, unsigned short* __restrict__ xrg,
    int* __restrict__ eorder_g, int* __restrict__ bstart_g,
    int* __restrict__ packCnt, int* __restrict__ egoOff,
    int* __restrict__ meta_node, int* __restrict__ meta_eid,
    unsigned int* __restrict__ We1p, unsigned int* __restrict__ We2h)
{
  __shared__ __align__(16) unsigned short xlL[NG_ * S1_];
  __shared__ __align__(16) unsigned short xrL[NG_ * S1_];
  __shared__ float xloc[NG_ * F_];
  __shared__ int   edst[EG_];
  __shared__ int   sNE, sStart;
  const int b = blockIdx.x, tid = threadIdx.x;
  const int n0 = b * NG_, eb = b * EG_;

  if (b == 0) {
    for (int i = tid; i < HC1_ / 2; i += 512) {      // channel pair
      const float* wA = &We1[(2 * i) * ED_];
      const float* wB = &We1[(2 * i + 1) * ED_];
      unsigned int* o = &We1p[i * 8];
#pragma unroll
      for (int k = 0; k < 6; ++k) o[k] = pack2h(wA[k], wB[k]);
      o[6] = pack2h(att1[2 * i], att1[2 * i + 1]);
      o[7] = 0;
    }
    for (int i = tid; i < C2_; i += 512) {
      const float* w = &We2[i * ED_];
      unsigned int* o = &We2h[i * 4];
      o[0] = pack2h(w[0], w[1]); o[1] = pack2h(w[2], w[3]); o[2] = pack2h(w[4], w[5]);
      o[3] = __float_as_uint(att2[i]);
    }
  }

  if (tid < EG_) edst[tid] = eidx[ET_ + eb + tid] - n0;
  xloc[tid] = x[n0 * F_ + tid];            // NG_*F_ == 512 == blockDim
  __syncthreads();

  if (tid < 448) {
    for (int t = 0; t < 2; ++t) {
      const int ch = tid + t * 448;
      if (ch >= 800) break;
      const bool isL = (ch < 400);
      const int  c   = isL ? ch : ch - 400;
      const float* Wp = (isL ? Wl1 : Wr1) + c * F_;
      const float bias = isL ? bl1[c] : br1[c];
      unsigned short* dst = (isL ? xlL : xrL) + c;
      float w[16];
#pragma unroll
      for (int qk = 0; qk < 4; ++qk) {
        float4 v = *(const float4*)(Wp + qk * 4);
        w[qk*4+0] = v.x; w[qk*4+1] = v.y; w[qk*4+2] = v.z; w[qk*4+3] = v.w;
      }
      for (int n = 0; n < NG_; n += 2) {
        const float* xa = &xloc[n * F_];
        float accA = bias, accB = bias;
#pragma unroll
        for (int qk = 0; qk < 4; ++qk) {
          float4 a  = *(const float4*)(xa + qk * 4);
          float4 bv = *(const float4*)(xa + F_ + qk * 4);
          accA = fmaf(a.x,  w[qk*4+0], accA); accA = fmaf(a.y,  w[qk*4+1], accA);
          accA = fmaf(a.z,  w[qk*4+2], accA); accA = fmaf(a.w,  w[qk*4+3], accA);
          accB = fmaf(bv.x, w[qk*4+0], accB); accB = fmaf(bv.y, w[qk*4+1], accB);
          accB = fmaf(bv.z, w[qk*4+2], accB); accB = fmaf(bv.w, w[qk*4+3], accB);
        }
        dst[n * S1_]       = f2h(accA);     // f16 (better mantissa than bf16)
        dst[(n + 1) * S1_] = f2h(accB);
      }
    }
  } else {
    const int lane = tid & 63;
    const int d    = lane & 31;
    const int half = lane >> 5;
    int cnt = 0;
    const int4* ed4 = (const int4*)edst;
    for (int i = 0; i < 32; ++i) {
      int4 v = ed4[half * 32 + i];
      cnt += (v.x == d) + (v.y == d) + (v.z == d) + (v.w == d);
    }
    const int cnt_lo = __shfl(cnt, d);
    const int total  = cnt + __shfl_xor(cnt, 32);
    int pre = total;
#pragma unroll
    for (int off = 1; off < 32; off <<= 1) {
      int tt = __shfl(pre, lane - off);
      if (d >= off) pre += tt;
    }
    const int start = pre - total;
    if (lane < 32) {
      bstart_g[b * 33 + d] = start;
      if (d == 31) bstart_g[b * 33 + 32] = pre;
      if (d == 0)  sNE = total;
    }
    int p = start + (half ? cnt_lo : 0);
    for (int i = 0; i < 32; ++i) {
      int4 v = ed4[half * 32 + i];
      const int e = half * 128 + i * 4;
      if (v.x == d) eorder_g[eb + p++] = e;
      if (v.y == d) eorder_g[eb + p++] = e + 1;
      if (v.z == d) eorder_g[eb + p++] = e + 2;
      if (v.w == d) eorder_g[eb + p++] = e + 3;
    }
  }
  __syncthreads();

  for (int i = tid; i < 3200; i += 512) {
    const bool isR = (i >= 1600);
    const int idx = isR ? i - 1600 : i;
    const int n = idx / 50, c8 = idx - n * 50;
    const ushort8v v = *(const ushort8v*)&(isR ? xrL : xlL)[n * S1_ + c8 * 8];
    *(ushort8v*)&(isR ? xrg : xlg)[(n0 + n) * SG_ + c8 * 8] = v;
  }

  if (tid == 0) sStart = atomicAdd(packCnt, sNE);
  __syncthreads();
  const int nE = sNE, st = sStart;
  if (tid == 0) egoOff[b] = st;
  if (tid < nE && st + nE <= CAP_) {
    const int e = eorder_g[eb + tid];
    meta_node[st + tid] = eidx[eb + e];
    meta_eid[st + tid]  = eb + e;
  }
}

// ---------------------------------------------------------------------------
// K2: edge scores + segment softmax + aggregation. One block/graph.
// Phase B fully packed-f16: channel pairs via v_pk_fma/add/mul + fdot2;
// leaky via exact identity max(p,0.2p) = 0.6p + 0.4|p| (abs = bit-mask).
// ---------------------------------------------------------------------------
__global__ __launch_bounds__(512, 2)
void k2_scores_aggregate(
    const unsigned short* __restrict__ xlg, const unsigned short* __restrict__ xrg,
    const int* __restrict__ eidx, const float* __restrict__ eattr,
    const unsigned int* __restrict__ We1p,
    const float* __restrict__ bc1,
    const int* __restrict__ eorder_g, const int* __restrict__ bstart_g,
    unsigned short* __restrict__ hg)
{
  __shared__ __align__(16) unsigned short xl[NG_ * S1_];
  __shared__ __align__(16) unsigned short xr[NG_ * S1_];
  __shared__ float sc0[EG_ * H1_];
  __shared__ float sc1[EG_ * H1_];
  __shared__ float ea[EG_ * ED_];
  __shared__ int   esrc[EG_], edst[EG_], eorder[EG_];
  __shared__ int   bstart[NG_ + 1];
  __shared__ float deninv[NG_ * H1_];

  const int b = blockIdx.x, tid = threadIdx.x;
  const int n0 = b * NG_, eb = b * EG_;

  for (int i = tid; i < 3200; i += 512) {
    const bool isR = (i >= 1600);
    const int idx = isR ? i - 1600 : i;
    const int n = idx / 50, c8 = idx - n * 50;
    const ushort8v v = *(const ushort8v*)&(isR ? xrg : xlg)[(n0 + n) * SG_ + c8 * 8];
    *(ushort8v*)&(isR ? xr : xl)[n * S1_ + c8 * 8] = v;
  }
  if (tid < EG_) {
    esrc[tid]   = eidx[eb + tid] - n0;
    edst[tid]   = eidx[ET_ + eb + tid] - n0;
    eorder[tid] = eorder_g[eb + tid];
  }
  for (int i = tid; i < EG_ * ED_; i += 512) ea[i] = eattr[eb * ED_ + i];
  if (tid < NG_ + 1) bstart[tid] = bstart_g[b * 33 + tid];
  __syncthreads();

  {
    const int e = tid & 255;
    const int s = __builtin_amdgcn_readfirstlane((int)(tid >> 8) & 1);
    float* const scp = s ? sc1 : sc0;
    const int sl = esrc[e], dl = edst[e];
    half2v eb6[6];
#pragma unroll
    for (int k = 0; k < 6; ++k) {
      const _Float16 v = (_Float16)ea[e * ED_ + k];
      eb6[k][0] = v; eb6[k][1] = v;                      // broadcast pair
    }
    const half2v c06 = {(_Float16)0.6f, (_Float16)0.6f};
    const half2v c04 = {(_Float16)0.4f, (_Float16)0.4f};
    const unsigned short* xlrow = &xl[sl * S1_ + s * 40];
    const unsigned short* xrrow = &xr[dl * S1_ + s * 40];
#pragma unroll
    for (int h = 0; h < H1_; ++h) {
      float sh = 0.f;
#pragma unroll
      for (int co = 0; co < 5; ++co) {
        const int coff  = h * C1_ + co * 8;              // even
        const int cbase = coff + s * 40;                 // even, uniform
        const uint4 av4 = __builtin_bit_cast(uint4, *(const ushort8v*)(xlrow + coff));
        const uint4 rv4 = __builtin_bit_cast(uint4, *(const ushort8v*)(xrrow + coff));
        const unsigned int avd[4] = {av4.x, av4.y, av4.z, av4.w};
        const unsigned int rvd[4] = {rv4.x, rv4.y, rv4.z, rv4.w};
        const unsigned int* wp = &We1p[(cbase >> 1) * 8];  // uniform -> s_load
#pragma unroll
        for (int u2 = 0; u2 < 4; ++u2) {
          const unsigned int* wq = wp + u2 * 8;
          half2v ep2 = u2h(wq[0]) * eb6[0];
          ep2 += u2h(wq[1]) * eb6[1];
          ep2 += u2h(wq[2]) * eb6[2];
          ep2 += u2h(wq[3]) * eb6[3];
          ep2 += u2h(wq[4]) * eb6[4];
          ep2 += u2h(wq[5]) * eb6[5];
          half2v p2 = (u2h(avd[u2]) + u2h(rvd[u2])) + ep2;
          const half2v pa = __builtin_bit_cast(half2v,
              __builtin_bit_cast(unsigned int, p2) & 0x7FFF7FFFu);
          p2 = p2 * c06 + pa * c04;                      // leaky
          sh = __builtin_amdgcn_fdot2(p2, u2h(wq[6]), sh, false);
        }
      }
      scp[e * H1_ + h] = sh;
    }
  }
  __syncthreads();

  if (tid < NG_ * H1_) {
    const int d = tid & 31, h = tid >> 5;
    const int s0 = bstart[d], s1 = bstart[d + 1];
    float m = -INFINITY;
    for (int k = s0; k < s1; ++k) {
      const int e5i = eorder[k] * H1_ + h;
      m = fmaxf(m, sc0[e5i] + sc1[e5i]);
    }
    float den = 0.f;
    for (int k = s0; k < s1; ++k) {
      const int e5i = eorder[k] * H1_ + h;
      float t = expf(sc0[e5i] + sc1[e5i] - m);
      den += t;
      sc0[e5i] = t;
    }
    deninv[tid] = 1.f / (den + 1e-16f);
  }
  __syncthreads();

  for (int idx = tid; idx < NG_ * 50; idx += 512) {
    const int d  = idx / 50;
    const int co = idx - d * 50;
    const int c  = co * 8;
    const int h  = co / 10;
    const int s0 = bstart[d], s1 = bstart[d + 1];
    float acc[8] = {0.f,0.f,0.f,0.f,0.f,0.f,0.f,0.f};
    for (int k = s0; k < s1; ++k) {
      const int e = eorder[k];
      const float al = sc0[e * H1_ + h];
      ushort8v xv = *(const ushort8v*)(&xl[esrc[e] * S1_ + c]);
#pragma unroll
      for (int u = 0; u < 8; ++u) acc[u] = fmaf(al, h2f(xv[u]), acc[u]);
    }
    const float inv = deninv[h * 32 + d];
    ushort8v hv;
#pragma unroll
    for (int u = 0; u < 8; ++u)
      hv[u] = f2bf(fmaxf(fmaf(acc[u], inv, bc1[c + u]), 0.f));
    *(ushort8v*)&hg[(n0 + d) * SG_ + c] = hv;
  }
}

// ---------------------------------------------------------------------------
// K3a: packed GEMM (unchanged; hg is bf16).
// ---------------------------------------------------------------------------
__global__ __launch_bounds__(512, 2)
void k3a_gemm(const unsigned short* __restrict__ hg,
              const int* __restrict__ meta_node, const int* __restrict__ packCnt,
              const float* __restrict__ Wl2, const float* __restrict__ bl2,
              const float* __restrict__ Wr2, const float* __restrict__ br2,
              float* __restrict__ msgP, float* __restrict__ xr2v_g)
{
  __shared__ __align__(16) unsigned short rows[64 * S1_];
  __shared__ int rnode[64];
  __shared__ int sTot;
  const int tid = threadIdx.x;
  const bool isX = (blockIdx.x < 16);
  if (tid == 0) sTot = *packCnt;
  __syncthreads();
  const int total = min(sTot, CAP_);

  const float* W    = isX ? Wr2 : Wl2;
  const float* bias = isX ? br2 : bl2;
  float* outB       = isX ? xr2v_g : msgP;

  const int es = tid & 15;
  const int cg = tid >> 4;
  const float* wp[5];
#pragma unroll
  for (int i = 0; i < 5; ++i) wp[i] = &W[(size_t)(cg * 5 + i) * HC1_];

  int c = isX ? (int)blockIdx.x : (int)blockIdx.x - 16;
  const int cstep = (int)gridDim.x - 16;

  for (;;) {
    const int r0 = c * 64;
    int nr;
    if (isX) nr = 64;
    else { if (r0 >= total) break; nr = min(64, total - r0); }

    __syncthreads();
    if (tid < 64) rnode[tid] = (tid < nr) ? (isX ? (r0 + tid) * NG_ : meta_node[r0 + tid]) : 0;
    __syncthreads();
    for (int i = tid; i < 64 * 50; i += 512) {
      const int r = i / 50, o8 = i - r * 50;
      if (r < nr)
        *(ushort8v*)&rows[r * S1_ + o8 * 8] =
            *(const ushort8v*)&hg[(size_t)rnode[r] * SG_ + o8 * 8];
    }
    __syncthreads();

    float acc[4][5] = {};
#pragma unroll 2
    for (int ko = 0; ko < 50; ++ko) {
      const int k = ko * 8;
      ushort8v rv[4];
#pragma unroll
      for (int t = 0; t < 4; ++t)
        rv[t] = *(const ushort8v*)&rows[(es + 16 * t) * S1_ + k];
#pragma unroll
      for (int i = 0; i < 5; ++i) {
        const float4 wa = *(const float4*)(wp[i] + k);
        const float4 wb = *(const float4*)(wp[i] + k + 4);
#pragma unroll
        for (int t = 0; t < 4; ++t)
          acc[t][i] = dot8(rv[t], wa, wb, acc[t][i]);
      }
    }

#pragma unroll
    for (int t = 0; t < 4; ++t) {
      const int r = es + 16 * t;
      if (r < nr) {
        float* op = outB + (size_t)(r0 + r) * C2_ + cg * 5;
#pragma unroll
        for (int i = 0; i < 5; ++i) op[i] = acc[t][i] + bias[cg * 5 + i];
      }
    }
    if (isX) break;
    c += cstep;
  }
}

// ---------------------------------------------------------------------------
// K34: fused per-graph layer-2 finisher + dense head + MLP (unchanged).
// ---------------------------------------------------------------------------
__global__ __launch_bounds__(512, 2)
void k34_finish_mlp(
    const float* __restrict__ eattr,
    const unsigned int* __restrict__ We2h,
    const float* __restrict__ bc2,
    const int* __restrict__ egoOff, const int* __restrict__ bstart_g,
    const int* __restrict__ meta_eid,
    const float* __restrict__ msgP, const float* __restrict__ xr2v_g,
    const float* __restrict__ Wd1, const float* __restrict__ bd1,
    const float* __restrict__ Wd2, const float* __restrict__ bd2,
    const float* __restrict__ Wf1, const float* __restrict__ bf1,
    const float* __restrict__ Wf2, const float* __restrict__ bf2,
    const float* __restrict__ Wm,  const float* __restrict__ bm,
    const float* __restrict__ Ws,  const float* __restrict__ bs,
    float* __restrict__ out)
{
  __shared__ float hE[4 * C2_];
  __shared__ float t1[4 * NG_];
  __shared__ float dbuf[4 * OBS_];
  __shared__ float f1b[4 * 256];
  __shared__ float f2b[4 * 256];
  __shared__ float xr2s[4 * C2_];
  __shared__ float scq[4 * EG_], wq4[4 * EG_];
  __shared__ float sInv[4];

  const int g0  = blockIdx.x * 4;
  const int tid = threadIdx.x;
  const int tg  = tid >> 7;
  const int lt  = tid & 127;
  const int g   = g0 + tg;
  const int off = egoOff[g];
  const int nE  = bstart_g[g * 33 + 1];

  if (lt < 40)
    *(float4*)&xr2s[tg * C2_ + lt * 4] = *(const float4*)&xr2v_g[(size_t)g * C2_ + lt * 4];
  __syncthreads();

  {
    const int s = lt >> 3, q8 = lt & 7;
    for (int base = 0; base < nE; base += 16) {
      const int j = base + s;
      float sv = 0.f;
      if (j < nE) {
        const int eid = meta_eid[off + j];
        const float* ap = &eattr[(size_t)eid * ED_];
        const half2v ea01 = { (_Float16)ap[0], (_Float16)ap[1] };
        const half2v ea23 = { (_Float16)ap[2], (_Float16)ap[3] };
        const half2v ea45 = { (_Float16)ap[4], (_Float16)ap[5] };
        const float* mrow = &msgP[(size_t)(off + j) * C2_];
        const float* xrv  = &xr2s[tg * C2_];
        for (int i = 0; i < 20; ++i) {
          const int c2 = q8 * 20 + i;
          const uint4 wv4 = *(const uint4*)&We2h[c2 * 4];
          float ep = __builtin_amdgcn_fdot2(u2h(wv4.z), ea45,
                     __builtin_amdgcn_fdot2(u2h(wv4.y), ea23,
                     __builtin_amdgcn_fdot2(u2h(wv4.x), ea01, 0.f, false), false), false);
          float pp = mrow[c2] + xrv[c2] + ep;
          pp = fmaxf(pp, 0.2f * pp);
          sv = fmaf(pp, __uint_as_float(wv4.w), sv);
        }
      }
      sv += __shfl_xor(sv, 1); sv += __shfl_xor(sv, 2); sv += __shfl_xor(sv, 4);
      if (q8 == 0 && j < nE) scq[tg * EG_ + j] = sv;
    }
  }
  __syncthreads();

  if (lt < 64) {
    float m = -INFINITY;
    for (int j = lt; j < nE; j += 64) m = fmaxf(m, scq[tg * EG_ + j]);
#pragma unroll
    for (int d = 1; d < 64; d <<= 1) m = fmaxf(m, __shfl_xor(m, d));
    float den = 0.f;
    for (int j = lt; j < nE; j += 64) {
      const float w = expf(scq[tg * EG_ + j] - m);
      wq4[tg * EG_ + j] = w;
      den += w;
    }
#pragma unroll
    for (int d = 1; d < 64; d <<= 1) den += __shfl_xor(den, d);
    if (lt == 0) sInv[tg] = 1.f / (den + 1e-16f);
  }
  __syncthreads();

  for (int c = lt; c < C2_; c += 128) {
    float o = 0.f;
    for (int j = 0; j < nE; ++j)
      o = fmaf(wq4[tg * EG_ + j], msgP[(size_t)(off + j) * C2_ + c], o);
    hE[tg * C2_ + c] = fmaxf(fmaf(o, sInv[tg], bc2[c]), 0.f);
  }
  __syncthreads();

  if (tid < 4 * NG_) {
    const int gg = tid >> 5, o = tid & 31;
    float acc = bd1[o];
    const float* w  = &Wd1[o * C2_];
    const float* hp = &hE[gg * C2_];
    for (int k = 0; k < C2_; k += 4) {
      float4 hv = *(const float4*)(hp + k);
      float4 wv = *(const float4*)(w + k);
      acc = fmaf(hv.x, wv.x, acc); acc = fmaf(hv.y, wv.y, acc);
      acc = fmaf(hv.z, wv.z, acc); acc = fmaf(hv.w, wv.w, acc);
    }
    t1[tid] = acc;
  }
  __syncthreads();

  for (int idx = tid; idx < 4 * OBS_; idx += 512) {
    const int gg = idx >> 9, o = idx & 511;
    float acc = bd2[o];
    const float* w  = &Wd2[o * NG_];
    const float* tp = &t1[gg * NG_];
#pragma unroll
    for (int k = 0; k < NG_; k += 4) {
      float4 tv = *(const float4*)(tp + k);
      float4 wv = *(const float4*)(w + k);
      acc = fmaf(tv.x, wv.x, acc); acc = fmaf(tv.y, wv.y, acc);
      acc = fmaf(tv.z, wv.z, acc); acc = fmaf(tv.w, wv.w, acc);
    }
    dbuf[idx] = tanhf(acc);
  }
  __syncthreads();

  {
    const int o = tid & 255, gg = tid >> 8;
    const float* w  = &Wf1[o * OBS_];
    const float* dA = &dbuf[(gg * 2 + 0) * OBS_];
    const float* dB = &dbuf[(gg * 2 + 1) * OBS_];
    float a0 = bf1[o], a1 = a0;
#pragma unroll 2
    for (int k = 0; k < OBS_; k += 4) {
      float4 wv = *(const float4*)(w + k);
      float4 xA = *(const float4*)(dA + k);
      float4 xB = *(const float4*)(dB + k);
      a0 = fmaf(xA.x, wv.x, a0); a0 = fmaf(xA.y, wv.y, a0);
      a0 = fmaf(xA.z, wv.z, a0); a0 = fmaf(xA.w, wv.w, a0);
      a1 = fmaf(xB.x, wv.x, a1); a1 = fmaf(xB.y, wv.y, a1);
      a1 = fmaf(xB.z, wv.z, a1); a1 = fmaf(xB.w, wv.w, a1);
    }
    f1b[(gg * 2 + 0) * 256 + o] = fmaxf(a0, 0.f);
    f1b[(gg * 2 + 1) * 256 + o] = fmaxf(a1, 0.f);
  }
  __syncthreads();

  {
    const int o = tid & 255, gg = tid >> 8;
    const float* w  = &Wf2[o * 256];
    const float* dA = &f1b[(gg * 2 + 0) * 256];
    const float* dB = &f1b[(gg * 2 + 1) * 256];
    float a0 = bf2[o], a1 = a0;
#pragma unroll 2
    for (int k = 0; k < 256; k += 4) {
      float4 wv = *(const float4*)(w + k);
      float4 xA = *(const float4*)(dA + k);
      float4 xB = *(const float4*)(dB + k);
      a0 = fmaf(xA.x, wv.x, a0); a0 = fmaf(xA.y, wv.y, a0);
      a0 = fmaf(xA.z, wv.z, a0); a0 = fmaf(xA.w, wv.w, a0);
      a1 = fmaf(xB.x, wv.x, a1); a1 = fmaf(xB.y, wv.y, a1);
      a1 = fmaf(xB.z, wv.z, a1); a1 = fmaf(xB.w, wv.w, a1);
    }
    f2b[(gg * 2 + 0) * 256 + o] = fmaxf(a0, 0.f);
    f2b[(gg * 2 + 1) * 256 + o] = fmaxf(a1, 0.f);
  }
  __syncthreads();

  if (tid < 16) {
    const int gg = tid >> 2;
    const int a  = (tid >> 1) & 1;
    const int hm = tid & 1;
    const float* fp = &f2b[gg * 256];
    const float* w  = hm ? &Ws[a * 256] : &Wm[a * 256];
    float acc = hm ? bs[a] : bm[a];
    for (int k = 0; k < 256; ++k) acc = fmaf(fp[k], w[k], acc);
    if (hm == 0) out[(g0 + gg) * 2 + a] = acc;
    else         out[2048 + (g0 + gg) * 2 + a] = -5.0f + 3.5f * (tanhf(acc) + 1.0f);
  }
}

extern "C" void kernel_launch(void* const* d_in, const int* in_sizes, int n_in,
                              void* d_out, int out_size, void* d_ws, size_t ws_size,
                              hipStream_t stream) {
  const float* x     = (const float*)d_in[0];
  const int*   eidx  = (const int*)d_in[1];
  const float* eattr = (const float*)d_in[2];
  const float* Wl1 = (const float*)d_in[3];  const float* bl1 = (const float*)d_in[4];
  const float* Wr1 = (const float*)d_in[5];  const float* br1 = (const float*)d_in[6];
  const float* We1 = (const float*)d_in[7];  const float* att1= (const float*)d_in[8];
  const float* bc1 = (const float*)d_in[9];
  const float* Wl2 = (const float*)d_in[10]; const float* bl2 = (const float*)d_in[11];
  const float* Wr2 = (const float*)d_in[12]; const float* br2 = (const float*)d_in[13];
  const float* We2 = (const float*)d_in[14]; const float* att2= (const float*)d_in[15];
  const float* bc2 = (const float*)d_in[16];
  const float* Wd1 = (const float*)d_in[17]; const float* bd1 = (const float*)d_in[18];
  const float* Wd2 = (const float*)d_in[19]; const float* bd2 = (const float*)d_in[20];
  const float* Wf1 = (const float*)d_in[21]; const float* bf1 = (const float*)d_in[22];
  const float* Wf2 = (const float*)d_in[23]; const float* bf2 = (const float*)d_in[24];
  const float* Wm  = (const float*)d_in[25]; const float* bm  = (const float*)d_in[26];
  const float* Ws  = (const float*)d_in[27]; const float* bs  = (const float*)d_in[28];

  // workspace layout (~82 MB)
  unsigned short* xlg = (unsigned short*)d_ws;          // [32768][400] f16 = 26.2 MB
  unsigned short* hg  = xlg + (size_t)32768 * SG_;      // xr (f16), then h (bf16)
  float* msgP   = (float*)(hg + (size_t)32768 * SG_);   // CAP_ x 160 f32 = 26.2 MB
  int* eorder_g = (int*)(msgP + (size_t)CAP_ * C2_);    // 1.05 MB
  int* bstart_g = eorder_g + ET_;                       // 132 KB
  float* egoHu  = (float*)(bstart_g + B_ * 33);         // 640 KB (layout keep)
  int* egoOff   = (int*)(egoHu + B_ * C2_);             // 4.1 KB
  int* meta_node= egoOff + (B_ + 1);                    // 160 KB
  int* meta_eid = meta_node + CAP_;                     // 160 KB
  float* xr2v_g = (float*)(meta_eid + CAP_);            // 640 KB
  int* packCnt  = (int*)(xr2v_g + B_ * C2_);            // 4 B
  unsigned int* We1p = (unsigned int*)(packCnt + 4);    // 6.4 KB (pair layout)
  unsigned int* We2h = We1p + (HC1_ / 2) * 8;           // 2.6 KB

  hipMemsetAsync(packCnt, 0, sizeof(int), stream);

  k1_transform_bucket<<<B_, 512, 0, stream>>>(
      x, eidx, Wl1, bl1, Wr1, br1, We1, att1, We2, att2,
      xlg, hg, eorder_g, bstart_g,
      packCnt, egoOff, meta_node, meta_eid, We1p, We2h);

  k2_scores_aggregate<<<B_, 512, 0, stream>>>(
      xlg, hg, eidx, eattr, We1p, bc1, eorder_g, bstart_g, hg);

  k3a_gemm<<<272, 512, 0, stream>>>(
      hg, meta_node, packCnt, Wl2, bl2, Wr2, br2, msgP, xr2v_g);

  k34_finish_mlp<<<B_ / 4, 512, 0, stream>>>(
      eattr, We2h, bc2, egoOff, bstart_g, meta_eid, msgP, xr2v_g,
      Wd1, bd1, Wd2, bd2, Wf1, bf1, Wf2, bf2, Wm, bm, Ws, bs,
      (float*)d_out);
}

// Round 18
// 213.041 us; speedup vs baseline: 1.0933x; 1.0364x over previous
//
#include <hip/hip_runtime.h>

#define B_    1024
#define NG_   32
#define F_    16
#define ED_   6
#define EG_   256
#define ET_   262144
#define H1_   5
#define C1_   80
#define HC1_  400
#define C2_   160
#define OBS_  512

#define S1_   408   // LDS f16 row stride (816B: 16B-aligned, 2-way-max bank alias)
#define SG_   400   // global f16/bf16 row stride
#define CAP_  40960 // packed ego-edge capacity (mean total ~8192)

typedef unsigned short ushort8v __attribute__((ext_vector_type(8)));
typedef _Float16 half2v __attribute__((ext_vector_type(2)));

__device__ __forceinline__ float bf2f(unsigned short u) {
  return __uint_as_float(((unsigned int)u) << 16);
}
__device__ __forceinline__ unsigned short f2bf(float f) {
  unsigned int u = __float_as_uint(f);
  u = u + 0x7FFFu + ((u >> 16) & 1u);   // RNE
  return (unsigned short)(u >> 16);
}
__device__ __forceinline__ unsigned short f2h(float f) {
  return __builtin_bit_cast(unsigned short, (_Float16)f);
}
__device__ __forceinline__ float h2f(unsigned short u) {
  return (float)__builtin_bit_cast(_Float16, u);
}
__device__ __forceinline__ unsigned int pack2h(float a, float b) {
  half2v h; h[0] = (_Float16)a; h[1] = (_Float16)b;
  return __builtin_bit_cast(unsigned int, h);
}
__device__ __forceinline__ half2v u2h(unsigned int u) {
  return __builtin_bit_cast(half2v, u);
}
__device__ __forceinline__ float dot8(ushort8v hv, float4 wa, float4 wb, float acc) {
  acc = fmaf(bf2f(hv[0]), wa.x, acc);
  acc = fmaf(bf2f(hv[1]), wa.y, acc);
  acc = fmaf(bf2f(hv[2]), wa.z, acc);
  acc = fmaf(bf2f(hv[3]), wa.w, acc);
  acc = fmaf(bf2f(hv[4]), wb.x, acc);
  acc = fmaf(bf2f(hv[5]), wb.y, acc);
  acc = fmaf(bf2f(hv[6]), wb.z, acc);
  acc = fmaf(bf2f(hv[7]), wb.w, acc);
  return acc;
}

// ---------------------------------------------------------------------------
// K1: node transforms (waves 0-6, into LDS, f16) + bucket build (wave 7) +
// coalesced LDS->global copy + atomic ego-edge meta packing. Blocks 0-3 also
// pre-pack weights: b0 = We1 pair-layout + We2h; b1/b2/b3 = k-major packed
// Wf1q/Wf2q/Wd2q for k34's coalesced MLP loads.
// ---------------------------------------------------------------------------
__global__ __launch_bounds__(512, 2)
void k1_transform_bucket(
    const float* __restrict__ x, const int* __restrict__ eidx,
    const float* __restrict__ Wl1, const float* __restrict__ bl1,
    const float* __restrict__ Wr1, const float* __restrict__ br1,
    const float* __restrict__ We1, const float* __restrict__ att1,
    const float* __restrict__ We2, const float* __restrict__ att2,
    const float* __restrict__ Wf1, const float* __restrict__ Wf2,
    const float* __restrict__ Wd2,
    unsigned short* __restrict__ xlg, unsigned short* __restrict__ xrg,
    int* __restrict__ eorder_g, int* __restrict__ bstart_g,
    int* __restrict__ packCnt, int* __restrict__ egoOff,
    int* __restrict__ meta_node, int* __restrict__ meta_eid,
    unsigned int* __restrict__ We1p, unsigned int* __restrict__ We2h,
    float4* __restrict__ Wf1q, float4* __restrict__ Wf2q,
    float4* __restrict__ Wd2q)
{
  __shared__ __align__(16) unsigned short xlL[NG_ * S1_];
  __shared__ __align__(16) unsigned short xrL[NG_ * S1_];
  __shared__ float xloc[NG_ * F_];
  __shared__ int   edst[EG_];
  __shared__ int   sNE, sStart;
  const int b = blockIdx.x, tid = threadIdx.x;
  const int n0 = b * NG_, eb = b * EG_;

  if (b == 0) {
    for (int i = tid; i < HC1_ / 2; i += 512) {      // channel pair
      const float* wA = &We1[(2 * i) * ED_];
      const float* wB = &We1[(2 * i + 1) * ED_];
      unsigned int* o = &We1p[i * 8];
#pragma unroll
      for (int k = 0; k < 6; ++k) o[k] = pack2h(wA[k], wB[k]);
      o[6] = pack2h(att1[2 * i], att1[2 * i + 1]);
      o[7] = 0;
    }
    for (int i = tid; i < C2_; i += 512) {
      const float* w = &We2[i * ED_];
      unsigned int* o = &We2h[i * 4];
      o[0] = pack2h(w[0], w[1]); o[1] = pack2h(w[2], w[3]); o[2] = pack2h(w[4], w[5]);
      o[3] = __float_as_uint(att2[i]);
    }
  } else if (b == 1) {
    for (int i = tid; i < 128 * 256; i += 512) {     // Wf1q[k4][o]
      const int k4 = i >> 8, o = i & 255;
      Wf1q[i] = *(const float4*)&Wf1[o * OBS_ + k4 * 4];
    }
  } else if (b == 2) {
    for (int i = tid; i < 64 * 256; i += 512) {      // Wf2q[k4][o]
      const int k4 = i >> 8, o = i & 255;
      Wf2q[i] = *(const float4*)&Wf2[o * 256 + k4 * 4];
    }
  } else if (b == 3) {
    for (int i = tid; i < 8 * 512; i += 512) {       // Wd2q[k4][o]
      const int k4 = i >> 9, o = i & 511;
      Wd2q[i] = *(const float4*)&Wd2[o * NG_ + k4 * 4];
    }
  }

  if (tid < EG_) edst[tid] = eidx[ET_ + eb + tid] - n0;
  xloc[tid] = x[n0 * F_ + tid];            // NG_*F_ == 512 == blockDim
  __syncthreads();

  if (tid < 448) {
    for (int t = 0; t < 2; ++t) {
      const int ch = tid + t * 448;
      if (ch >= 800) break;
      const bool isL = (ch < 400);
      const int  c   = isL ? ch : ch - 400;
      const float* Wp = (isL ? Wl1 : Wr1) + c * F_;
      const float bias = isL ? bl1[c] : br1[c];
      unsigned short* dst = (isL ? xlL : xrL) + c;
      float w[16];
#pragma unroll
      for (int qk = 0; qk < 4; ++qk) {
        float4 v = *(const float4*)(Wp + qk * 4);
        w[qk*4+0] = v.x; w[qk*4+1] = v.y; w[qk*4+2] = v.z; w[qk*4+3] = v.w;
      }
      for (int n = 0; n < NG_; n += 2) {
        const float* xa = &xloc[n * F_];
        float accA = bias, accB = bias;
#pragma unroll
        for (int qk = 0; qk < 4; ++qk) {
          float4 a  = *(const float4*)(xa + qk * 4);
          float4 bv = *(const float4*)(xa + F_ + qk * 4);
          accA = fmaf(a.x,  w[qk*4+0], accA); accA = fmaf(a.y,  w[qk*4+1], accA);
          accA = fmaf(a.z,  w[qk*4+2], accA); accA = fmaf(a.w,  w[qk*4+3], accA);
          accB = fmaf(bv.x, w[qk*4+0], accB); accB = fmaf(bv.y, w[qk*4+1], accB);
          accB = fmaf(bv.z, w[qk*4+2], accB); accB = fmaf(bv.w, w[qk*4+3], accB);
        }
        dst[n * S1_]       = f2h(accA);
        dst[(n + 1) * S1_] = f2h(accB);
      }
    }
  } else {
    const int lane = tid & 63;
    const int d    = lane & 31;
    const int half = lane >> 5;
    int cnt = 0;
    const int4* ed4 = (const int4*)edst;
    for (int i = 0; i < 32; ++i) {
      int4 v = ed4[half * 32 + i];
      cnt += (v.x == d) + (v.y == d) + (v.z == d) + (v.w == d);
    }
    const int cnt_lo = __shfl(cnt, d);
    const int total  = cnt + __shfl_xor(cnt, 32);
    int pre = total;
#pragma unroll
    for (int off = 1; off < 32; off <<= 1) {
      int tt = __shfl(pre, lane - off);
      if (d >= off) pre += tt;
    }
    const int start = pre - total;
    if (lane < 32) {
      bstart_g[b * 33 + d] = start;
      if (d == 31) bstart_g[b * 33 + 32] = pre;
      if (d == 0)  sNE = total;
    }
    int p = start + (half ? cnt_lo : 0);
    for (int i = 0; i < 32; ++i) {
      int4 v = ed4[half * 32 + i];
      const int e = half * 128 + i * 4;
      if (v.x == d) eorder_g[eb + p++] = e;
      if (v.y == d) eorder_g[eb + p++] = e + 1;
      if (v.z == d) eorder_g[eb + p++] = e + 2;
      if (v.w == d) eorder_g[eb + p++] = e + 3;
    }
  }
  __syncthreads();

  for (int i = tid; i < 3200; i += 512) {
    const bool isR = (i >= 1600);
    const int idx = isR ? i - 1600 : i;
    const int n = idx / 50, c8 = idx - n * 50;
    const ushort8v v = *(const ushort8v*)&(isR ? xrL : xlL)[n * S1_ + c8 * 8];
    *(ushort8v*)&(isR ? xrg : xlg)[(n0 + n) * SG_ + c8 * 8] = v;
  }

  if (tid == 0) sStart = atomicAdd(packCnt, sNE);
  __syncthreads();
  const int nE = sNE, st = sStart;
  if (tid == 0) egoOff[b] = st;
  if (tid < nE && st + nE <= CAP_) {
    const int e = eorder_g[eb + tid];
    meta_node[st + tid] = eidx[eb + e];
    meta_eid[st + tid]  = eb + e;
  }
}

// ---------------------------------------------------------------------------
// K2: edge scores + segment softmax + aggregation. One block/graph.
// Phase B fully packed-f16 (pairs via v_pk ops + fdot2; leaky = 0.6p+0.4|p|).
// ---------------------------------------------------------------------------
__global__ __launch_bounds__(512, 2)
void k2_scores_aggregate(
    const unsigned short* __restrict__ xlg, const unsigned short* __restrict__ xrg,
    const int* __restrict__ eidx, const float* __restrict__ eattr,
    const unsigned int* __restrict__ We1p,
    const float* __restrict__ bc1,
    const int* __restrict__ eorder_g, const int* __restrict__ bstart_g,
    unsigned short* __restrict__ hg)
{
  __shared__ __align__(16) unsigned short xl[NG_ * S1_];
  __shared__ __align__(16) unsigned short xr[NG_ * S1_];
  __shared__ float sc0[EG_ * H1_];
  __shared__ float sc1[EG_ * H1_];
  __shared__ float ea[EG_ * ED_];
  __shared__ int   esrc[EG_], edst[EG_], eorder[EG_];
  __shared__ int   bstart[NG_ + 1];
  __shared__ float deninv[NG_ * H1_];

  const int b = blockIdx.x, tid = threadIdx.x;
  const int n0 = b * NG_, eb = b * EG_;

  for (int i = tid; i < 3200; i += 512) {
    const bool isR = (i >= 1600);
    const int idx = isR ? i - 1600 : i;
    const int n = idx / 50, c8 = idx - n * 50;
    const ushort8v v = *(const ushort8v*)&(isR ? xrg : xlg)[(n0 + n) * SG_ + c8 * 8];
    *(ushort8v*)&(isR ? xr : xl)[n * S1_ + c8 * 8] = v;
  }
  if (tid < EG_) {
    esrc[tid]   = eidx[eb + tid] - n0;
    edst[tid]   = eidx[ET_ + eb + tid] - n0;
    eorder[tid] = eorder_g[eb + tid];
  }
  for (int i = tid; i < EG_ * ED_; i += 512) ea[i] = eattr[eb * ED_ + i];
  if (tid < NG_ + 1) bstart[tid] = bstart_g[b * 33 + tid];
  __syncthreads();

  {
    const int e = tid & 255;
    const int s = __builtin_amdgcn_readfirstlane((int)(tid >> 8) & 1);
    float* const scp = s ? sc1 : sc0;
    const int sl = esrc[e], dl = edst[e];
    half2v eb6[6];
#pragma unroll
    for (int k = 0; k < 6; ++k) {
      const _Float16 v = (_Float16)ea[e * ED_ + k];
      eb6[k][0] = v; eb6[k][1] = v;
    }
    const half2v c06 = {(_Float16)0.6f, (_Float16)0.6f};
    const half2v c04 = {(_Float16)0.4f, (_Float16)0.4f};
    const unsigned short* xlrow = &xl[sl * S1_ + s * 40];
    const unsigned short* xrrow = &xr[dl * S1_ + s * 40];
#pragma unroll
    for (int h = 0; h < H1_; ++h) {
      float sh = 0.f;
#pragma unroll
      for (int co = 0; co < 5; ++co) {
        const int coff  = h * C1_ + co * 8;
        const int cbase = coff + s * 40;
        const uint4 av4 = __builtin_bit_cast(uint4, *(const ushort8v*)(xlrow + coff));
        const uint4 rv4 = __builtin_bit_cast(uint4, *(const ushort8v*)(xrrow + coff));
        const unsigned int avd[4] = {av4.x, av4.y, av4.z, av4.w};
        const unsigned int rvd[4] = {rv4.x, rv4.y, rv4.z, rv4.w};
        const unsigned int* wp = &We1p[(cbase >> 1) * 8];
#pragma unroll
        for (int u2 = 0; u2 < 4; ++u2) {
          const unsigned int* wq = wp + u2 * 8;
          half2v ep2 = u2h(wq[0]) * eb6[0];
          ep2 += u2h(wq[1]) * eb6[1];
          ep2 += u2h(wq[2]) * eb6[2];
          ep2 += u2h(wq[3]) * eb6[3];
          ep2 += u2h(wq[4]) * eb6[4];
          ep2 += u2h(wq[5]) * eb6[5];
          half2v p2 = (u2h(avd[u2]) + u2h(rvd[u2])) + ep2;
          const half2v pa = __builtin_bit_cast(half2v,
              __builtin_bit_cast(unsigned int, p2) & 0x7FFF7FFFu);
          p2 = p2 * c06 + pa * c04;
          sh = __builtin_amdgcn_fdot2(p2, u2h(wq[6]), sh, false);
        }
      }
      scp[e * H1_ + h] = sh;
    }
  }
  __syncthreads();

  if (tid < NG_ * H1_) {
    const int d = tid & 31, h = tid >> 5;
    const int s0 = bstart[d], s1 = bstart[d + 1];
    float m = -INFINITY;
    for (int k = s0; k < s1; ++k) {
      const int e5i = eorder[k] * H1_ + h;
      m = fmaxf(m, sc0[e5i] + sc1[e5i]);
    }
    float den = 0.f;
    for (int k = s0; k < s1; ++k) {
      const int e5i = eorder[k] * H1_ + h;
      float t = expf(sc0[e5i] + sc1[e5i] - m);
      den += t;
      sc0[e5i] = t;
    }
    deninv[tid] = 1.f / (den + 1e-16f);
  }
  __syncthreads();

  for (int idx = tid; idx < NG_ * 50; idx += 512) {
    const int d  = idx / 50;
    const int co = idx - d * 50;
    const int c  = co * 8;
    const int h  = co / 10;
    const int s0 = bstart[d], s1 = bstart[d + 1];
    float acc[8] = {0.f,0.f,0.f,0.f,0.f,0.f,0.f,0.f};
    for (int k = s0; k < s1; ++k) {
      const int e = eorder[k];
      const float al = sc0[e * H1_ + h];
      ushort8v xv = *(const ushort8v*)(&xl[esrc[e] * S1_ + c]);
#pragma unroll
      for (int u = 0; u < 8; ++u) acc[u] = fmaf(al, h2f(xv[u]), acc[u]);
    }
    const float inv = deninv[h * 32 + d];
    ushort8v hv;
#pragma unroll
    for (int u = 0; u < 8; ++u)
      hv[u] = f2bf(fmaxf(fmaf(acc[u], inv, bc1[c + u]), 0.f));
    *(ushort8v*)&hg[(n0 + d) * SG_ + c] = hv;
  }
}

// ---------------------------------------------------------------------------
// K3a: packed GEMM (unchanged; hg is bf16).
// ---------------------------------------------------------------------------
__global__ __launch_bounds__(512, 2)
void k3a_gemm(const unsigned short* __restrict__ hg,
              const int* __restrict__ meta_node, const int* __restrict__ packCnt,
              const float* __restrict__ Wl2, const float* __restrict__ bl2,
              const float* __restrict__ Wr2, const float* __restrict__ br2,
              float* __restrict__ msgP, float* __restrict__ xr2v_g)
{
  __shared__ __align__(16) unsigned short rows[64 * S1_];
  __shared__ int rnode[64];
  __shared__ int sTot;
  const int tid = threadIdx.x;
  const bool isX = (blockIdx.x < 16);
  if (tid == 0) sTot = *packCnt;
  __syncthreads();
  const int total = min(sTot, CAP_);

  const float* W    = isX ? Wr2 : Wl2;
  const float* bias = isX ? br2 : bl2;
  float* outB       = isX ? xr2v_g : msgP;

  const int es = tid & 15;
  const int cg = tid >> 4;
  const float* wp[5];
#pragma unroll
  for (int i = 0; i < 5; ++i) wp[i] = &W[(size_t)(cg * 5 + i) * HC1_];

  int c = isX ? (int)blockIdx.x : (int)blockIdx.x - 16;
  const int cstep = (int)gridDim.x - 16;

  for (;;) {
    const int r0 = c * 64;
    int nr;
    if (isX) nr = 64;
    else { if (r0 >= total) break; nr = min(64, total - r0); }

    __syncthreads();
    if (tid < 64) rnode[tid] = (tid < nr) ? (isX ? (r0 + tid) * NG_ : meta_node[r0 + tid]) : 0;
    __syncthreads();
    for (int i = tid; i < 64 * 50; i += 512) {
      const int r = i / 50, o8 = i - r * 50;
      if (r < nr)
        *(ushort8v*)&rows[r * S1_ + o8 * 8] =
            *(const ushort8v*)&hg[(size_t)rnode[r] * SG_ + o8 * 8];
    }
    __syncthreads();

    float acc[4][5] = {};
#pragma unroll 2
    for (int ko = 0; ko < 50; ++ko) {
      const int k = ko * 8;
      ushort8v rv[4];
#pragma unroll
      for (int t = 0; t < 4; ++t)
        rv[t] = *(const ushort8v*)&rows[(es + 16 * t) * S1_ + k];
#pragma unroll
      for (int i = 0; i < 5; ++i) {
        const float4 wa = *(const float4*)(wp[i] + k);
        const float4 wb = *(const float4*)(wp[i] + k + 4);
#pragma unroll
        for (int t = 0; t < 4; ++t)
          acc[t][i] = dot8(rv[t], wa, wb, acc[t][i]);
      }
    }

#pragma unroll
    for (int t = 0; t < 4; ++t) {
      const int r = es + 16 * t;
      if (r < nr) {
        float* op = outB + (size_t)(r0 + r) * C2_ + cg * 5;
#pragma unroll
        for (int i = 0; i < 5; ++i) op[i] = acc[t][i] + bias[cg * 5 + i];
      }
    }
    if (isX) break;
    c += cstep;
  }
}

// ---------------------------------------------------------------------------
// K34: fused per-graph layer-2 finisher + dense head + MLP. MLP weight loads
// now k-major packed (Wf1q/Wf2q/Wd2q) -> lane-consecutive coalesced float4
// (r17: per-thread row streaming fanned each wave-load to 64 cache lines).
// ---------------------------------------------------------------------------
__global__ __launch_bounds__(512, 2)
void k34_finish_mlp(
    const float* __restrict__ eattr,
    const unsigned int* __restrict__ We2h,
    const float* __restrict__ bc2,
    const int* __restrict__ egoOff, const int* __restrict__ bstart_g,
    const int* __restrict__ meta_eid,
    const float* __restrict__ msgP, const float* __restrict__ xr2v_g,
    const float* __restrict__ Wd1, const float* __restrict__ bd1,
    const float4* __restrict__ Wd2q, const float* __restrict__ bd2,
    const float4* __restrict__ Wf1q, const float* __restrict__ bf1,
    const float4* __restrict__ Wf2q, const float* __restrict__ bf2,
    const float* __restrict__ Wm,  const float* __restrict__ bm,
    const float* __restrict__ Ws,  const float* __restrict__ bs,
    float* __restrict__ out)
{
  __shared__ float hE[4 * C2_];
  __shared__ float t1[4 * NG_];
  __shared__ float dbuf[4 * OBS_];
  __shared__ float f1b[4 * 256];
  __shared__ float f2b[4 * 256];
  __shared__ float xr2s[4 * C2_];
  __shared__ float scq[4 * EG_], wq4[4 * EG_];
  __shared__ float sInv[4];

  const int g0  = blockIdx.x * 4;
  const int tid = threadIdx.x;
  const int tg  = tid >> 7;
  const int lt  = tid & 127;
  const int g   = g0 + tg;
  const int off = egoOff[g];
  const int nE  = bstart_g[g * 33 + 1];

  if (lt < 40)
    *(float4*)&xr2s[tg * C2_ + lt * 4] = *(const float4*)&xr2v_g[(size_t)g * C2_ + lt * 4];
  __syncthreads();

  {
    const int s = lt >> 3, q8 = lt & 7;
    for (int base = 0; base < nE; base += 16) {
      const int j = base + s;
      float sv = 0.f;
      if (j < nE) {
        const int eid = meta_eid[off + j];
        const float* ap = &eattr[(size_t)eid * ED_];
        const half2v ea01 = { (_Float16)ap[0], (_Float16)ap[1] };
        const half2v ea23 = { (_Float16)ap[2], (_Float16)ap[3] };
        const half2v ea45 = { (_Float16)ap[4], (_Float16)ap[5] };
        const float* mrow = &msgP[(size_t)(off + j) * C2_];
        const float* xrv  = &xr2s[tg * C2_];
        for (int i = 0; i < 20; ++i) {
          const int c2 = q8 * 20 + i;
          const uint4 wv4 = *(const uint4*)&We2h[c2 * 4];
          float ep = __builtin_amdgcn_fdot2(u2h(wv4.z), ea45,
                     __builtin_amdgcn_fdot2(u2h(wv4.y), ea23,
                     __builtin_amdgcn_fdot2(u2h(wv4.x), ea01, 0.f, false), false), false);
          float pp = mrow[c2] + xrv[c2] + ep;
          pp = fmaxf(pp, 0.2f * pp);
          sv = fmaf(pp, __uint_as_float(wv4.w), sv);
        }
      }
      sv += __shfl_xor(sv, 1); sv += __shfl_xor(sv, 2); sv += __shfl_xor(sv, 4);
      if (q8 == 0 && j < nE) scq[tg * EG_ + j] = sv;
    }
  }
  __syncthreads();

  if (lt < 64) {
    float m = -INFINITY;
    for (int j = lt; j < nE; j += 64) m = fmaxf(m, scq[tg * EG_ + j]);
#pragma unroll
    for (int d = 1; d < 64; d <<= 1) m = fmaxf(m, __shfl_xor(m, d));
    float den = 0.f;
    for (int j = lt; j < nE; j += 64) {
      const float w = expf(scq[tg * EG_ + j] - m);
      wq4[tg * EG_ + j] = w;
      den += w;
    }
#pragma unroll
    for (int d = 1; d < 64; d <<= 1) den += __shfl_xor(den, d);
    if (lt == 0) sInv[tg] = 1.f / (den + 1e-16f);
  }
  __syncthreads();

  for (int c = lt; c < C2_; c += 128) {
    float o = 0.f;
    for (int j = 0; j < nE; ++j)
      o = fmaf(wq4[tg * EG_ + j], msgP[(size_t)(off + j) * C2_ + c], o);
    hE[tg * C2_ + c] = fmaxf(fmaf(o, sInv[tg], bc2[c]), 0.f);
  }
  __syncthreads();

  // ---- t1 = ego @ Wd1^T + bd1 ----
  if (tid < 4 * NG_) {
    const int gg = tid >> 5, o = tid & 31;
    float acc = bd1[o];
    const float* w  = &Wd1[o * C2_];
    const float* hp = &hE[gg * C2_];
    for (int k = 0; k < C2_; k += 4) {
      float4 hv = *(const float4*)(hp + k);
      float4 wv = *(const float4*)(w + k);
      acc = fmaf(hv.x, wv.x, acc); acc = fmaf(hv.y, wv.y, acc);
      acc = fmaf(hv.z, wv.z, acc); acc = fmaf(hv.w, wv.w, acc);
    }
    t1[tid] = acc;
  }
  __syncthreads();

  // ---- d = tanh(t1 @ Wd2^T + bd2), coalesced k-major weights ----
  for (int idx = tid; idx < 4 * OBS_; idx += 512) {
    const int gg = idx >> 9, o = idx & 511;
    float acc = bd2[o];
    const float* tp = &t1[gg * NG_];
#pragma unroll
    for (int k4 = 0; k4 < 8; ++k4) {
      float4 wv = Wd2q[k4 * 512 + o];
      float4 tv = *(const float4*)(tp + k4 * 4);
      acc = fmaf(tv.x, wv.x, acc); acc = fmaf(tv.y, wv.y, acc);
      acc = fmaf(tv.z, wv.z, acc); acc = fmaf(tv.w, wv.w, acc);
    }
    dbuf[idx] = tanhf(acc);
  }
  __syncthreads();

  // ---- f1 = relu(d @ Wf1^T + bf1), coalesced k-major weights ----
  {
    const int o = tid & 255, gg = tid >> 8;
    const float* dA = &dbuf[(gg * 2 + 0) * OBS_];
    const float* dB = &dbuf[(gg * 2 + 1) * OBS_];
    float a0 = bf1[o], a1 = a0;
#pragma unroll 2
    for (int k4 = 0; k4 < 128; ++k4) {
      float4 wv = Wf1q[k4 * 256 + o];
      float4 xA = *(const float4*)(dA + k4 * 4);
      float4 xB = *(const float4*)(dB + k4 * 4);
      a0 = fmaf(xA.x, wv.x, a0); a0 = fmaf(xA.y, wv.y, a0);
      a0 = fmaf(xA.z, wv.z, a0); a0 = fmaf(xA.w, wv.w, a0);
      a1 = fmaf(xB.x, wv.x, a1); a1 = fmaf(xB.y, wv.y, a1);
      a1 = fmaf(xB.z, wv.z, a1); a1 = fmaf(xB.w, wv.w, a1);
    }
    f1b[(gg * 2 + 0) * 256 + o] = fmaxf(a0, 0.f);
    f1b[(gg * 2 + 1) * 256 + o] = fmaxf(a1, 0.f);
  }
  __syncthreads();

  // ---- f2 = relu(f1 @ Wf2^T + bf2), coalesced k-major weights ----
  {
    const int o = tid & 255, gg = tid >> 8;
    const float* dA = &f1b[(gg * 2 + 0) * 256];
    const float* dB = &f1b[(gg * 2 + 1) * 256];
    float a0 = bf2[o], a1 = a0;
#pragma unroll 2
    for (int k4 = 0; k4 < 64; ++k4) {
      float4 wv = Wf2q[k4 * 256 + o];
      float4 xA = *(const float4*)(dA + k4 * 4);
      float4 xB = *(const float4*)(dB + k4 * 4);
      a0 = fmaf(xA.x, wv.x, a0); a0 = fmaf(xA.y, wv.y, a0);
      a0 = fmaf(xA.z, wv.z, a0); a0 = fmaf(xA.w, wv.w, a0);
      a1 = fmaf(xB.x, wv.x, a1); a1 = fmaf(xB.y, wv.y, a1);
      a1 = fmaf(xB.z, wv.z, a1); a1 = fmaf(xB.w, wv.w, a1);
    }
    f2b[(gg * 2 + 0) * 256 + o] = fmaxf(a0, 0.f);
    f2b[(gg * 2 + 1) * 256 + o] = fmaxf(a1, 0.f);
  }
  __syncthreads();

  if (tid < 16) {
    const int gg = tid >> 2;
    const int a  = (tid >> 1) & 1;
    const int hm = tid & 1;
    const float* fp = &f2b[gg * 256];
    const float* w  = hm ? &Ws[a * 256] : &Wm[a * 256];
    float acc = hm ? bs[a] : bm[a];
    for (int k = 0; k < 256; ++k) acc = fmaf(fp[k], w[k], acc);
    if (hm == 0) out[(g0 + gg) * 2 + a] = acc;
    else         out[2048 + (g0 + gg) * 2 + a] = -5.0f + 3.5f * (tanhf(acc) + 1.0f);
  }
}

extern "C" void kernel_launch(void* const* d_in, const int* in_sizes, int n_in,
                              void* d_out, int out_size, void* d_ws, size_t ws_size,
                              hipStream_t stream) {
  const float* x     = (const float*)d_in[0];
  const int*   eidx  = (const int*)d_in[1];
  const float* eattr = (const float*)d_in[2];
  const float* Wl1 = (const float*)d_in[3];  const float* bl1 = (const float*)d_in[4];
  const float* Wr1 = (const float*)d_in[5];  const float* br1 = (const float*)d_in[6];
  const float* We1 = (const float*)d_in[7];  const float* att1= (const float*)d_in[8];
  const float* bc1 = (const float*)d_in[9];
  const float* Wl2 = (const float*)d_in[10]; const float* bl2 = (const float*)d_in[11];
  const float* Wr2 = (const float*)d_in[12]; const float* br2 = (const float*)d_in[13];
  const float* We2 = (const float*)d_in[14]; const float* att2= (const float*)d_in[15];
  const float* bc2 = (const float*)d_in[16];
  const float* Wd1 = (const float*)d_in[17]; const float* bd1 = (const float*)d_in[18];
  const float* Wd2 = (const float*)d_in[19]; const float* bd2 = (const float*)d_in[20];
  const float* Wf1 = (const float*)d_in[21]; const float* bf1 = (const float*)d_in[22];
  const float* Wf2 = (const float*)d_in[23]; const float* bf2 = (const float*)d_in[24];
  const float* Wm  = (const float*)d_in[25]; const float* bm  = (const float*)d_in[26];
  const float* Ws  = (const float*)d_in[27]; const float* bs  = (const float*)d_in[28];

  // workspace layout (~83 MB)
  unsigned short* xlg = (unsigned short*)d_ws;          // [32768][400] f16 = 26.2 MB
  unsigned short* hg  = xlg + (size_t)32768 * SG_;      // xr (f16), then h (bf16)
  float* msgP   = (float*)(hg + (size_t)32768 * SG_);   // CAP_ x 160 f32 = 26.2 MB
  int* eorder_g = (int*)(msgP + (size_t)CAP_ * C2_);    // 1.05 MB
  int* bstart_g = eorder_g + ET_;                       // 132 KB
  float4* Wf1q  = (float4*)(bstart_g + B_ * 33 + 3);    // 512 KB (16B-aligned: offset mult of 4 ints)
  float4* Wf2q  = Wf1q + 128 * 256;                     // 256 KB
  float4* Wd2q  = Wf2q + 64 * 256;                      // 64 KB
  int* egoOff   = (int*)(Wd2q + 8 * 512);               // 4.1 KB
  int* meta_node= egoOff + (B_ + 1);                    // 160 KB
  int* meta_eid = meta_node + CAP_;                     // 160 KB
  float* xr2v_g = (float*)(meta_eid + CAP_);            // 640 KB
  int* packCnt  = (int*)(xr2v_g + B_ * C2_);            // 4 B
  unsigned int* We1p = (unsigned int*)(packCnt + 4);    // 6.4 KB (pair layout)
  unsigned int* We2h = We1p + (HC1_ / 2) * 8;           // 2.6 KB

  hipMemsetAsync(packCnt, 0, sizeof(int), stream);

  k1_transform_bucket<<<B_, 512, 0, stream>>>(
      x, eidx, Wl1, bl1, Wr1, br1, We1, att1, We2, att2, Wf1, Wf2, Wd2,
      xlg, hg, eorder_g, bstart_g,
      packCnt, egoOff, meta_node, meta_eid, We1p, We2h, Wf1q, Wf2q, Wd2q);

  k2_scores_aggregate<<<B_, 512, 0, stream>>>(
      xlg, hg, eidx, eattr, We1p, bc1, eorder_g, bstart_g, hg);

  k3a_gemm<<<272, 512, 0, stream>>>(
      hg, meta_node, packCnt, Wl2, bl2, Wr2, br2, msgP, xr2v_g);

  k34_finish_mlp<<<B_ / 4, 512, 0, stream>>>(
      eattr, We2h, bc2, egoOff, bstart_g, meta_eid, msgP, xr2v_g,
      Wd1, bd1, Wd2q, bd2, Wf1q, bf1, Wf2q, bf2, Wm, bm, Ws, bs,
      (float*)d_out);
}

// Round 19
// 206.744 us; speedup vs baseline: 1.1266x; 1.0305x over previous
//
#include <hip/hip_runtime.h>

#define B_    1024
#define NG_   32
#define F_    16
#define ED_   6
#define EG_   256
#define ET_   262144
#define H1_   5
#define C1_   80
#define HC1_  400
#define C2_   160
#define OBS_  512

#define S1_   408   // LDS f16 row stride (816B: 16B-aligned, 2-way-max bank alias)
#define SG_   400   // global f16/bf16 row stride
#define CAP_  40960 // packed ego-edge capacity (mean total ~8192)

typedef unsigned short ushort8v __attribute__((ext_vector_type(8)));
typedef _Float16 half2v __attribute__((ext_vector_type(2)));

__device__ __forceinline__ float bf2f(unsigned short u) {
  return __uint_as_float(((unsigned int)u) << 16);
}
__device__ __forceinline__ unsigned short f2bf(float f) {
  unsigned int u = __float_as_uint(f);
  u = u + 0x7FFFu + ((u >> 16) & 1u);   // RNE
  return (unsigned short)(u >> 16);
}
__device__ __forceinline__ unsigned short f2h(float f) {
  return __builtin_bit_cast(unsigned short, (_Float16)f);
}
__device__ __forceinline__ float h2f(unsigned short u) {
  return (float)__builtin_bit_cast(_Float16, u);
}
__device__ __forceinline__ unsigned int pack2h(float a, float b) {
  half2v h; h[0] = (_Float16)a; h[1] = (_Float16)b;
  return __builtin_bit_cast(unsigned int, h);
}
__device__ __forceinline__ half2v u2h(unsigned int u) {
  return __builtin_bit_cast(half2v, u);
}
__device__ __forceinline__ float dot8(ushort8v hv, float4 wa, float4 wb, float acc) {
  acc = fmaf(bf2f(hv[0]), wa.x, acc);
  acc = fmaf(bf2f(hv[1]), wa.y, acc);
  acc = fmaf(bf2f(hv[2]), wa.z, acc);
  acc = fmaf(bf2f(hv[3]), wa.w, acc);
  acc = fmaf(bf2f(hv[4]), wb.x, acc);
  acc = fmaf(bf2f(hv[5]), wb.y, acc);
  acc = fmaf(bf2f(hv[6]), wb.z, acc);
  acc = fmaf(bf2f(hv[7]), wb.w, acc);
  return acc;
}

// ---------------------------------------------------------------------------
// K1: node transforms (waves 0-6, into LDS, f16) + bucket build (wave 7) +
// coalesced LDS->global copy + atomic ego-edge meta packing. Weight packing
// spread across 200+ blocks (r18: blocks 1-3 each did the whole transpose
// with divergent loads -> 50+ us stragglers gating the kernel boundary).
// ---------------------------------------------------------------------------
__global__ __launch_bounds__(512, 2)
void k1_transform_bucket(
    const float* __restrict__ x, const int* __restrict__ eidx,
    const float* __restrict__ Wl1, const float* __restrict__ bl1,
    const float* __restrict__ Wr1, const float* __restrict__ br1,
    const float* __restrict__ We1, const float* __restrict__ att1,
    const float* __restrict__ We2, const float* __restrict__ att2,
    const float* __restrict__ Wf1, const float* __restrict__ Wf2,
    const float* __restrict__ Wd2,
    unsigned short* __restrict__ xlg, unsigned short* __restrict__ xrg,
    int* __restrict__ eorder_g, int* __restrict__ bstart_g,
    int* __restrict__ packCnt, int* __restrict__ egoOff,
    int* __restrict__ meta_node, int* __restrict__ meta_eid,
    unsigned int* __restrict__ We1p, unsigned int* __restrict__ We2h,
    float4* __restrict__ Wf1q, float4* __restrict__ Wf2q,
    float4* __restrict__ Wd2q)
{
  __shared__ __align__(16) unsigned short xlL[NG_ * S1_];
  __shared__ __align__(16) unsigned short xrL[NG_ * S1_];
  __shared__ float xloc[NG_ * F_];
  __shared__ int   edst[EG_];
  __shared__ int   sNE, sStart;
  const int b = blockIdx.x, tid = threadIdx.x;
  const int n0 = b * NG_, eb = b * EG_;

  if (b == 0) {
    for (int i = tid; i < HC1_ / 2; i += 512) {      // channel pair
      const float* wA = &We1[(2 * i) * ED_];
      const float* wB = &We1[(2 * i + 1) * ED_];
      unsigned int* o = &We1p[i * 8];
#pragma unroll
      for (int k = 0; k < 6; ++k) o[k] = pack2h(wA[k], wB[k]);
      o[6] = pack2h(att1[2 * i], att1[2 * i + 1]);
      o[7] = 0;
    }
    for (int i = tid; i < C2_; i += 512) {
      const float* w = &We2[i * ED_];
      unsigned int* o = &We2h[i * 4];
      o[0] = pack2h(w[0], w[1]); o[1] = pack2h(w[2], w[3]); o[2] = pack2h(w[4], w[5]);
      o[3] = __float_as_uint(att2[i]);
    }
  } else if (b >= 8 && b < 136) {                    // Wf1q: one k4 per block
    const int k4 = b - 8;
    if (tid < 256) Wf1q[k4 * 256 + tid] = *(const float4*)&Wf1[tid * OBS_ + k4 * 4];
  } else if (b >= 136 && b < 200) {                  // Wf2q: one k4 per block
    const int k4 = b - 136;
    if (tid < 256) Wf2q[k4 * 256 + tid] = *(const float4*)&Wf2[tid * 256 + k4 * 4];
  } else if (b >= 200 && b < 208) {                  // Wd2q: one k4 per block
    const int k4 = b - 200;
    Wd2q[k4 * 512 + tid] = *(const float4*)&Wd2[tid * NG_ + k4 * 4];
  }

  if (tid < EG_) edst[tid] = eidx[ET_ + eb + tid] - n0;
  xloc[tid] = x[n0 * F_ + tid];            // NG_*F_ == 512 == blockDim
  __syncthreads();

  if (tid < 448) {
    for (int t = 0; t < 2; ++t) {
      const int ch = tid + t * 448;
      if (ch >= 800) break;
      const bool isL = (ch < 400);
      const int  c   = isL ? ch : ch - 400;
      const float* Wp = (isL ? Wl1 : Wr1) + c * F_;
      const float bias = isL ? bl1[c] : br1[c];
      unsigned short* dst = (isL ? xlL : xrL) + c;
      float w[16];
#pragma unroll
      for (int qk = 0; qk < 4; ++qk) {
        float4 v = *(const float4*)(Wp + qk * 4);
        w[qk*4+0] = v.x; w[qk*4+1] = v.y; w[qk*4+2] = v.z; w[qk*4+3] = v.w;
      }
      for (int n = 0; n < NG_; n += 2) {
        const float* xa = &xloc[n * F_];
        float accA = bias, accB = bias;
#pragma unroll
        for (int qk = 0; qk < 4; ++qk) {
          float4 a  = *(const float4*)(xa + qk * 4);
          float4 bv = *(const float4*)(xa + F_ + qk * 4);
          accA = fmaf(a.x,  w[qk*4+0], accA); accA = fmaf(a.y,  w[qk*4+1], accA);
          accA = fmaf(a.z,  w[qk*4+2], accA); accA = fmaf(a.w,  w[qk*4+3], accA);
          accB = fmaf(bv.x, w[qk*4+0], accB); accB = fmaf(bv.y, w[qk*4+1], accB);
          accB = fmaf(bv.z, w[qk*4+2], accB); accB = fmaf(bv.w, w[qk*4+3], accB);
        }
        dst[n * S1_]       = f2h(accA);
        dst[(n + 1) * S1_] = f2h(accB);
      }
    }
  } else {
    const int lane = tid & 63;
    const int d    = lane & 31;
    const int half = lane >> 5;
    int cnt = 0;
    const int4* ed4 = (const int4*)edst;
    for (int i = 0; i < 32; ++i) {
      int4 v = ed4[half * 32 + i];
      cnt += (v.x == d) + (v.y == d) + (v.z == d) + (v.w == d);
    }
    const int cnt_lo = __shfl(cnt, d);
    const int total  = cnt + __shfl_xor(cnt, 32);
    int pre = total;
#pragma unroll
    for (int off = 1; off < 32; off <<= 1) {
      int tt = __shfl(pre, lane - off);
      if (d >= off) pre += tt;
    }
    const int start = pre - total;
    if (lane < 32) {
      bstart_g[b * 33 + d] = start;
      if (d == 31) bstart_g[b * 33 + 32] = pre;
      if (d == 0)  sNE = total;
    }
    int p = start + (half ? cnt_lo : 0);
    for (int i = 0; i < 32; ++i) {
      int4 v = ed4[half * 32 + i];
      const int e = half * 128 + i * 4;
      if (v.x == d) eorder_g[eb + p++] = e;
      if (v.y == d) eorder_g[eb + p++] = e + 1;
      if (v.z == d) eorder_g[eb + p++] = e + 2;
      if (v.w == d) eorder_g[eb + p++] = e + 3;
    }
  }
  __syncthreads();

  for (int i = tid; i < 3200; i += 512) {
    const bool isR = (i >= 1600);
    const int idx = isR ? i - 1600 : i;
    const int n = idx / 50, c8 = idx - n * 50;
    const ushort8v v = *(const ushort8v*)&(isR ? xrL : xlL)[n * S1_ + c8 * 8];
    *(ushort8v*)&(isR ? xrg : xlg)[(n0 + n) * SG_ + c8 * 8] = v;
  }

  if (tid == 0) sStart = atomicAdd(packCnt, sNE);
  __syncthreads();
  const int nE = sNE, st = sStart;
  if (tid == 0) egoOff[b] = st;
  if (tid < nE && st + nE <= CAP_) {
    const int e = eorder_g[eb + tid];
    meta_node[st + tid] = eidx[eb + e];
    meta_eid[st + tid]  = eb + e;
  }
}

// ---------------------------------------------------------------------------
// K2: edge scores + segment softmax + aggregation. One block/graph.
// Phase B fully packed-f16 (pairs via v_pk ops + fdot2; leaky = 0.6p+0.4|p|).
// ---------------------------------------------------------------------------
__global__ __launch_bounds__(512, 2)
void k2_scores_aggregate(
    const unsigned short* __restrict__ xlg, const unsigned short* __restrict__ xrg,
    const int* __restrict__ eidx, const float* __restrict__ eattr,
    const unsigned int* __restrict__ We1p,
    const float* __restrict__ bc1,
    const int* __restrict__ eorder_g, const int* __restrict__ bstart_g,
    unsigned short* __restrict__ hg)
{
  __shared__ __align__(16) unsigned short xl[NG_ * S1_];
  __shared__ __align__(16) unsigned short xr[NG_ * S1_];
  __shared__ float sc0[EG_ * H1_];
  __shared__ float sc1[EG_ * H1_];
  __shared__ float ea[EG_ * ED_];
  __shared__ int   esrc[EG_], edst[EG_], eorder[EG_];
  __shared__ int   bstart[NG_ + 1];
  __shared__ float deninv[NG_ * H1_];

  const int b = blockIdx.x, tid = threadIdx.x;
  const int n0 = b * NG_, eb = b * EG_;

  for (int i = tid; i < 3200; i += 512) {
    const bool isR = (i >= 1600);
    const int idx = isR ? i - 1600 : i;
    const int n = idx / 50, c8 = idx - n * 50;
    const ushort8v v = *(const ushort8v*)&(isR ? xrg : xlg)[(n0 + n) * SG_ + c8 * 8];
    *(ushort8v*)&(isR ? xr : xl)[n * S1_ + c8 * 8] = v;
  }
  if (tid < EG_) {
    esrc[tid]   = eidx[eb + tid] - n0;
    edst[tid]   = eidx[ET_ + eb + tid] - n0;
    eorder[tid] = eorder_g[eb + tid];
  }
  for (int i = tid; i < EG_ * ED_; i += 512) ea[i] = eattr[eb * ED_ + i];
  if (tid < NG_ + 1) bstart[tid] = bstart_g[b * 33 + tid];
  __syncthreads();

  {
    const int e = tid & 255;
    const int s = __builtin_amdgcn_readfirstlane((int)(tid >> 8) & 1);
    float* const scp = s ? sc1 : sc0;
    const int sl = esrc[e], dl = edst[e];
    half2v eb6[6];
#pragma unroll
    for (int k = 0; k < 6; ++k) {
      const _Float16 v = (_Float16)ea[e * ED_ + k];
      eb6[k][0] = v; eb6[k][1] = v;
    }
    const half2v c06 = {(_Float16)0.6f, (_Float16)0.6f};
    const half2v c04 = {(_Float16)0.4f, (_Float16)0.4f};
    const unsigned short* xlrow = &xl[sl * S1_ + s * 40];
    const unsigned short* xrrow = &xr[dl * S1_ + s * 40];
#pragma unroll
    for (int h = 0; h < H1_; ++h) {
      float sh = 0.f;
#pragma unroll
      for (int co = 0; co < 5; ++co) {
        const int coff  = h * C1_ + co * 8;
        const int cbase = coff + s * 40;
        const uint4 av4 = __builtin_bit_cast(uint4, *(const ushort8v*)(xlrow + coff));
        const uint4 rv4 = __builtin_bit_cast(uint4, *(const ushort8v*)(xrrow + coff));
        const unsigned int avd[4] = {av4.x, av4.y, av4.z, av4.w};
        const unsigned int rvd[4] = {rv4.x, rv4.y, rv4.z, rv4.w};
        const unsigned int* wp = &We1p[(cbase >> 1) * 8];
#pragma unroll
        for (int u2 = 0; u2 < 4; ++u2) {
          const unsigned int* wq = wp + u2 * 8;
          half2v ep2 = u2h(wq[0]) * eb6[0];
          ep2 += u2h(wq[1]) * eb6[1];
          ep2 += u2h(wq[2]) * eb6[2];
          ep2 += u2h(wq[3]) * eb6[3];
          ep2 += u2h(wq[4]) * eb6[4];
          ep2 += u2h(wq[5]) * eb6[5];
          half2v p2 = (u2h(avd[u2]) + u2h(rvd[u2])) + ep2;
          const half2v pa = __builtin_bit_cast(half2v,
              __builtin_bit_cast(unsigned int, p2) & 0x7FFF7FFFu);
          p2 = p2 * c06 + pa * c04;
          sh = __builtin_amdgcn_fdot2(p2, u2h(wq[6]), sh, false);
        }
      }
      scp[e * H1_ + h] = sh;
    }
  }
  __syncthreads();

  if (tid < NG_ * H1_) {
    const int d = tid & 31, h = tid >> 5;
    const int s0 = bstart[d], s1 = bstart[d + 1];
    float m = -INFINITY;
    for (int k = s0; k < s1; ++k) {
      const int e5i = eorder[k] * H1_ + h;
      m = fmaxf(m, sc0[e5i] + sc1[e5i]);
    }
    float den = 0.f;
    for (int k = s0; k < s1; ++k) {
      const int e5i = eorder[k] * H1_ + h;
      float t = expf(sc0[e5i] + sc1[e5i] - m);
      den += t;
      sc0[e5i] = t;
    }
    deninv[tid] = 1.f / (den + 1e-16f);
  }
  __syncthreads();

  for (int idx = tid; idx < NG_ * 50; idx += 512) {
    const int d  = idx / 50;
    const int co = idx - d * 50;
    const int c  = co * 8;
    const int h  = co / 10;
    const int s0 = bstart[d], s1 = bstart[d + 1];
    float acc[8] = {0.f,0.f,0.f,0.f,0.f,0.f,0.f,0.f};
    for (int k = s0; k < s1; ++k) {
      const int e = eorder[k];
      const float al = sc0[e * H1_ + h];
      ushort8v xv = *(const ushort8v*)(&xl[esrc[e] * S1_ + c]);
#pragma unroll
      for (int u = 0; u < 8; ++u) acc[u] = fmaf(al, h2f(xv[u]), acc[u]);
    }
    const float inv = deninv[h * 32 + d];
    ushort8v hv;
#pragma unroll
    for (int u = 0; u < 8; ++u)
      hv[u] = f2bf(fmaxf(fmaf(acc[u], inv, bc1[c + u]), 0.f));
    *(ushort8v*)&hg[(n0 + d) * SG_ + c] = hv;
  }
}

// ---------------------------------------------------------------------------
// K3a: packed GEMM (unchanged; hg is bf16).
// ---------------------------------------------------------------------------
__global__ __launch_bounds__(512, 2)
void k3a_gemm(const unsigned short* __restrict__ hg,
              const int* __restrict__ meta_node, const int* __restrict__ packCnt,
              const float* __restrict__ Wl2, const float* __restrict__ bl2,
              const float* __restrict__ Wr2, const float* __restrict__ br2,
              float* __restrict__ msgP, float* __restrict__ xr2v_g)
{
  __shared__ __align__(16) unsigned short rows[64 * S1_];
  __shared__ int rnode[64];
  __shared__ int sTot;
  const int tid = threadIdx.x;
  const bool isX = (blockIdx.x < 16);
  if (tid == 0) sTot = *packCnt;
  __syncthreads();
  const int total = min(sTot, CAP_);

  const float* W    = isX ? Wr2 : Wl2;
  const float* bias = isX ? br2 : bl2;
  float* outB       = isX ? xr2v_g : msgP;

  const int es = tid & 15;
  const int cg = tid >> 4;
  const float* wp[5];
#pragma unroll
  for (int i = 0; i < 5; ++i) wp[i] = &W[(size_t)(cg * 5 + i) * HC1_];

  int c = isX ? (int)blockIdx.x : (int)blockIdx.x - 16;
  const int cstep = (int)gridDim.x - 16;

  for (;;) {
    const int r0 = c * 64;
    int nr;
    if (isX) nr = 64;
    else { if (r0 >= total) break; nr = min(64, total - r0); }

    __syncthreads();
    if (tid < 64) rnode[tid] = (tid < nr) ? (isX ? (r0 + tid) * NG_ : meta_node[r0 + tid]) : 0;
    __syncthreads();
    for (int i = tid; i < 64 * 50; i += 512) {
      const int r = i / 50, o8 = i - r * 50;
      if (r < nr)
        *(ushort8v*)&rows[r * S1_ + o8 * 8] =
            *(const ushort8v*)&hg[(size_t)rnode[r] * SG_ + o8 * 8];
    }
    __syncthreads();

    float acc[4][5] = {};
#pragma unroll 2
    for (int ko = 0; ko < 50; ++ko) {
      const int k = ko * 8;
      ushort8v rv[4];
#pragma unroll
      for (int t = 0; t < 4; ++t)
        rv[t] = *(const ushort8v*)&rows[(es + 16 * t) * S1_ + k];
#pragma unroll
      for (int i = 0; i < 5; ++i) {
        const float4 wa = *(const float4*)(wp[i] + k);
        const float4 wb = *(const float4*)(wp[i] + k + 4);
#pragma unroll
        for (int t = 0; t < 4; ++t)
          acc[t][i] = dot8(rv[t], wa, wb, acc[t][i]);
      }
    }

#pragma unroll
    for (int t = 0; t < 4; ++t) {
      const int r = es + 16 * t;
      if (r < nr) {
        float* op = outB + (size_t)(r0 + r) * C2_ + cg * 5;
#pragma unroll
        for (int i = 0; i < 5; ++i) op[i] = acc[t][i] + bias[cg * 5 + i];
      }
    }
    if (isX) break;
    c += cstep;
  }
}

// ---------------------------------------------------------------------------
// K34: fused per-graph layer-2 finisher + dense head + MLP; k-major packed
// MLP weights (coalesced float4).
// ---------------------------------------------------------------------------
__global__ __launch_bounds__(512, 2)
void k34_finish_mlp(
    const float* __restrict__ eattr,
    const unsigned int* __restrict__ We2h,
    const float* __restrict__ bc2,
    const int* __restrict__ egoOff, const int* __restrict__ bstart_g,
    const int* __restrict__ meta_eid,
    const float* __restrict__ msgP, const float* __restrict__ xr2v_g,
    const float* __restrict__ Wd1, const float* __restrict__ bd1,
    const float4* __restrict__ Wd2q, const float* __restrict__ bd2,
    const float4* __restrict__ Wf1q, const float* __restrict__ bf1,
    const float4* __restrict__ Wf2q, const float* __restrict__ bf2,
    const float* __restrict__ Wm,  const float* __restrict__ bm,
    const float* __restrict__ Ws,  const float* __restrict__ bs,
    float* __restrict__ out)
{
  __shared__ float hE[4 * C2_];
  __shared__ float t1[4 * NG_];
  __shared__ float dbuf[4 * OBS_];
  __shared__ float f1b[4 * 256];
  __shared__ float f2b[4 * 256];
  __shared__ float xr2s[4 * C2_];
  __shared__ float scq[4 * EG_], wq4[4 * EG_];
  __shared__ float sInv[4];

  const int g0  = blockIdx.x * 4;
  const int tid = threadIdx.x;
  const int tg  = tid >> 7;
  const int lt  = tid & 127;
  const int g   = g0 + tg;
  const int off = egoOff[g];
  const int nE  = bstart_g[g * 33 + 1];

  if (lt < 40)
    *(float4*)&xr2s[tg * C2_ + lt * 4] = *(const float4*)&xr2v_g[(size_t)g * C2_ + lt * 4];
  __syncthreads();

  {
    const int s = lt >> 3, q8 = lt & 7;
    for (int base = 0; base < nE; base += 16) {
      const int j = base + s;
      float sv = 0.f;
      if (j < nE) {
        const int eid = meta_eid[off + j];
        const float* ap = &eattr[(size_t)eid * ED_];
        const half2v ea01 = { (_Float16)ap[0], (_Float16)ap[1] };
        const half2v ea23 = { (_Float16)ap[2], (_Float16)ap[3] };
        const half2v ea45 = { (_Float16)ap[4], (_Float16)ap[5] };
        const float* mrow = &msgP[(size_t)(off + j) * C2_];
        const float* xrv  = &xr2s[tg * C2_];
        for (int i = 0; i < 20; ++i) {
          const int c2 = q8 * 20 + i;
          const uint4 wv4 = *(const uint4*)&We2h[c2 * 4];
          float ep = __builtin_amdgcn_fdot2(u2h(wv4.z), ea45,
                     __builtin_amdgcn_fdot2(u2h(wv4.y), ea23,
                     __builtin_amdgcn_fdot2(u2h(wv4.x), ea01, 0.f, false), false), false);
          float pp = mrow[c2] + xrv[c2] + ep;
          pp = fmaxf(pp, 0.2f * pp);
          sv = fmaf(pp, __uint_as_float(wv4.w), sv);
        }
      }
      sv += __shfl_xor(sv, 1); sv += __shfl_xor(sv, 2); sv += __shfl_xor(sv, 4);
      if (q8 == 0 && j < nE) scq[tg * EG_ + j] = sv;
    }
  }
  __syncthreads();

  if (lt < 64) {
    float m = -INFINITY;
    for (int j = lt; j < nE; j += 64) m = fmaxf(m, scq[tg * EG_ + j]);
#pragma unroll
    for (int d = 1; d < 64; d <<= 1) m = fmaxf(m, __shfl_xor(m, d));
    float den = 0.f;
    for (int j = lt; j < nE; j += 64) {
      const float w = expf(scq[tg * EG_ + j] - m);
      wq4[tg * EG_ + j] = w;
      den += w;
    }
#pragma unroll
    for (int d = 1; d < 64; d <<= 1) den += __shfl_xor(den, d);
    if (lt == 0) sInv[tg] = 1.f / (den + 1e-16f);
  }
  __syncthreads();

  for (int c = lt; c < C2_; c += 128) {
    float o = 0.f;
    for (int j = 0; j < nE; ++j)
      o = fmaf(wq4[tg * EG_ + j], msgP[(size_t)(off + j) * C2_ + c], o);
    hE[tg * C2_ + c] = fmaxf(fmaf(o, sInv[tg], bc2[c]), 0.f);
  }
  __syncthreads();

  if (tid < 4 * NG_) {
    const int gg = tid >> 5, o = tid & 31;
    float acc = bd1[o];
    const float* w  = &Wd1[o * C2_];
    const float* hp = &hE[gg * C2_];
    for (int k = 0; k < C2_; k += 4) {
      float4 hv = *(const float4*)(hp + k);
      float4 wv = *(const float4*)(w + k);
      acc = fmaf(hv.x, wv.x, acc); acc = fmaf(hv.y, wv.y, acc);
      acc = fmaf(hv.z, wv.z, acc); acc = fmaf(hv.w, wv.w, acc);
    }
    t1[tid] = acc;
  }
  __syncthreads();

  for (int idx = tid; idx < 4 * OBS_; idx += 512) {
    const int gg = idx >> 9, o = idx & 511;
    float acc = bd2[o];
    const float* tp = &t1[gg * NG_];
#pragma unroll
    for (int k4 = 0; k4 < 8; ++k4) {
      float4 wv = Wd2q[k4 * 512 + o];
      float4 tv = *(const float4*)(tp + k4 * 4);
      acc = fmaf(tv.x, wv.x, acc); acc = fmaf(tv.y, wv.y, acc);
      acc = fmaf(tv.z, wv.z, acc); acc = fmaf(tv.w, wv.w, acc);
    }
    dbuf[idx] = tanhf(acc);
  }
  __syncthreads();

  {
    const int o = tid & 255, gg = tid >> 8;
    const float* dA = &dbuf[(gg * 2 + 0) * OBS_];
    const float* dB = &dbuf[(gg * 2 + 1) * OBS_];
    float a0 = bf1[o], a1 = a0;
#pragma unroll 2
    for (int k4 = 0; k4 < 128; ++k4) {
      float4 wv = Wf1q[k4 * 256 + o];
      float4 xA = *(const float4*)(dA + k4 * 4);
      float4 xB = *(const float4*)(dB + k4 * 4);
      a0 = fmaf(xA.x, wv.x, a0); a0 = fmaf(xA.y, wv.y, a0);
      a0 = fmaf(xA.z, wv.z, a0); a0 = fmaf(xA.w, wv.w, a0);
      a1 = fmaf(xB.x, wv.x, a1); a1 = fmaf(xB.y, wv.y, a1);
      a1 = fmaf(xB.z, wv.z, a1); a1 = fmaf(xB.w, wv.w, a1);
    }
    f1b[(gg * 2 + 0) * 256 + o] = fmaxf(a0, 0.f);
    f1b[(gg * 2 + 1) * 256 + o] = fmaxf(a1, 0.f);
  }
  __syncthreads();

  {
    const int o = tid & 255, gg = tid >> 8;
    const float* dA = &f1b[(gg * 2 + 0) * 256];
    const float* dB = &f1b[(gg * 2 + 1) * 256];
    float a0 = bf2[o], a1 = a0;
#pragma unroll 2
    for (int k4 = 0; k4 < 64; ++k4) {
      float4 wv = Wf2q[k4 * 256 + o];
      float4 xA = *(const float4*)(dA + k4 * 4);
      float4 xB = *(const float4*)(dB + k4 * 4);
      a0 = fmaf(xA.x, wv.x, a0); a0 = fmaf(xA.y, wv.y, a0);
      a0 = fmaf(xA.z, wv.z, a0); a0 = fmaf(xA.w, wv.w, a0);
      a1 = fmaf(xB.x, wv.x, a1); a1 = fmaf(xB.y, wv.y, a1);
      a1 = fmaf(xB.z, wv.z, a1); a1 = fmaf(xB.w, wv.w, a1);
    }
    f2b[(gg * 2 + 0) * 256 + o] = fmaxf(a0, 0.f);
    f2b[(gg * 2 + 1) * 256 + o] = fmaxf(a1, 0.f);
  }
  __syncthreads();

  if (tid < 16) {
    const int gg = tid >> 2;
    const int a  = (tid >> 1) & 1;
    const int hm = tid & 1;
    const float* fp = &f2b[gg * 256];
    const float* w  = hm ? &Ws[a * 256] : &Wm[a * 256];
    float acc = hm ? bs[a] : bm[a];
    for (int k = 0; k < 256; ++k) acc = fmaf(fp[k], w[k], acc);
    if (hm == 0) out[(g0 + gg) * 2 + a] = acc;
    else         out[2048 + (g0 + gg) * 2 + a] = -5.0f + 3.5f * (tanhf(acc) + 1.0f);
  }
}

extern "C" void kernel_launch(void* const* d_in, const int* in_sizes, int n_in,
                              void* d_out, int out_size, void* d_ws, size_t ws_size,
                              hipStream_t stream) {
  const float* x     = (const float*)d_in[0];
  const int*   eidx  = (const int*)d_in[1];
  const float* eattr = (const float*)d_in[2];
  const float* Wl1 = (const float*)d_in[3];  const float* bl1 = (const float*)d_in[4];
  const float* Wr1 = (const float*)d_in[5];  const float* br1 = (const float*)d_in[6];
  const float* We1 = (const float*)d_in[7];  const float* att1= (const float*)d_in[8];
  const float* bc1 = (const float*)d_in[9];
  const float* Wl2 = (const float*)d_in[10]; const float* bl2 = (const float*)d_in[11];
  const float* Wr2 = (const float*)d_in[12]; const float* br2 = (const float*)d_in[13];
  const float* We2 = (const float*)d_in[14]; const float* att2= (const float*)d_in[15];
  const float* bc2 = (const float*)d_in[16];
  const float* Wd1 = (const float*)d_in[17]; const float* bd1 = (const float*)d_in[18];
  const float* Wd2 = (const float*)d_in[19]; const float* bd2 = (const float*)d_in[20];
  const float* Wf1 = (const float*)d_in[21]; const float* bf1 = (const float*)d_in[22];
  const float* Wf2 = (const float*)d_in[23]; const float* bf2 = (const float*)d_in[24];
  const float* Wm  = (const float*)d_in[25]; const float* bm  = (const float*)d_in[26];
  const float* Ws  = (const float*)d_in[27]; const float* bs  = (const float*)d_in[28];

  // workspace layout (~83 MB)
  unsigned short* xlg = (unsigned short*)d_ws;          // [32768][400] f16 = 26.2 MB
  unsigned short* hg  = xlg + (size_t)32768 * SG_;      // xr (f16), then h (bf16)
  float* msgP   = (float*)(hg + (size_t)32768 * SG_);   // CAP_ x 160 f32 = 26.2 MB
  int* eorder_g = (int*)(msgP + (size_t)CAP_ * C2_);    // 1.05 MB
  int* bstart_g = eorder_g + ET_;                       // 132 KB
  float4* Wf1q  = (float4*)(bstart_g + B_ * 33 + 3);    // 512 KB (16B-aligned)
  float4* Wf2q  = Wf1q + 128 * 256;                     // 256 KB
  float4* Wd2q  = Wf2q + 64 * 256;                      // 64 KB
  int* egoOff   = (int*)(Wd2q + 8 * 512);               // 4.1 KB
  int* meta_node= egoOff + (B_ + 1);                    // 160 KB
  int* meta_eid = meta_node + CAP_;                     // 160 KB
  float* xr2v_g = (float*)(meta_eid + CAP_);            // 640 KB
  int* packCnt  = (int*)(xr2v_g + B_ * C2_);            // 4 B
  unsigned int* We1p = (unsigned int*)(packCnt + 4);    // 6.4 KB (pair layout)
  unsigned int* We2h = We1p + (HC1_ / 2) * 8;           // 2.6 KB

  hipMemsetAsync(packCnt, 0, sizeof(int), stream);

  k1_transform_bucket<<<B_, 512, 0, stream>>>(
      x, eidx, Wl1, bl1, Wr1, br1, We1, att1, We2, att2, Wf1, Wf2, Wd2,
      xlg, hg, eorder_g, bstart_g,
      packCnt, egoOff, meta_node, meta_eid, We1p, We2h, Wf1q, Wf2q, Wd2q);

  k2_scores_aggregate<<<B_, 512, 0, stream>>>(
      xlg, hg, eidx, eattr, We1p, bc1, eorder_g, bstart_g, hg);

  k3a_gemm<<<272, 512, 0, stream>>>(
      hg, meta_node, packCnt, Wl2, bl2, Wr2, br2, msgP, xr2v_g);

  k34_finish_mlp<<<B_ / 4, 512, 0, stream>>>(
      eattr, We2h, bc2, egoOff, bstart_g, meta_eid, msgP, xr2v_g,
      Wd1, bd1, Wd2q, bd2, Wf1q, bf1, Wf2q, bf2, Wm, bm, Ws, bs,
      (float*)d_out);
}